// Round 15
// baseline (294.979 us; speedup 1.0000x reference)
//
#include <hip/hip_runtime.h>
#include <hip/hip_bf16.h>

#define N_PTS   65536
#define LATENT  128
#define HIDDEN  512
#define OUT_D   64
#define NBUCKET 1024
#define ROWS_A  32

typedef __attribute__((ext_vector_type(8))) short frag_ab;   // 8 bf16
typedef __attribute__((ext_vector_type(4))) float f32x4;

__device__ __forceinline__ short bf16h(float f) {
    union { float f; unsigned u; } c; c.f = f;
    const unsigned r = (c.u + 0x7FFFu + ((c.u >> 16) & 1u)) >> 16;  // RNE
    return (short)r;
}
__device__ __forceinline__ float bf16tof(short s) {
    union { unsigned u; float f; } c; c.u = ((unsigned)(unsigned short)s) << 16;
    return c.f;
}

// ---------------- kernel P: pack W1/W2 -> per-chunk swizzled-linear frag stream ----------------
__global__ __launch_bounds__(256) void prep_weights(
    const float* __restrict__ W1, const float* __restrict__ W2,
    short* __restrict__ wfrag)
{
    const int tid = blockIdx.x * 256 + threadIdx.x;   // 0..24575
    const int c = tid / 1536;
    const int u = tid % 1536;
    frag_ab hi, lo;
    if (u < 1024) {
        const int l = u >> 4, slot = u & 15;
        const int j = slot ^ (l & 7);
        const int ct = j >> 3, ks = (j >> 1) & 3, hl = j & 1;
        const int n = (c * 2 + ct) * 16 + (l & 15);
        const int k0 = ks * 32 + ((l >> 4) << 3);
#pragma unroll
        for (int e = 0; e < 8; ++e) {
            const float wv = W1[(size_t)(k0 + e) * HIDDEN + n];
            const short h = bf16h(wv);
            hi[e] = h;
            lo[e] = bf16h(wv - bf16tof(h));
        }
        ((frag_ab*)wfrag)[(size_t)c * 1536 + u] = hl ? lo : hi;
    } else {
        const int u2 = u - 1024;
        const int l = u2 >> 3, slot = u2 & 7;
        const int j = slot ^ (l & 7);
        const int ot = j >> 1, hl = j & 1;
        const int n = ot * 16 + (l & 15);
#pragma unroll
        for (int e = 0; e < 8; ++e) {
            const int k = c * 32 + ((e >> 2) << 4) + ((l >> 4) << 2) + (e & 3);
            const float wv = W2[(size_t)k * OUT_D + n];
            const short h = bf16h(wv);
            hi[e] = h;
            lo[e] = bf16h(wv - bf16tof(h));
        }
        ((frag_ab*)wfrag)[(size_t)c * 1536 + u] = hl ? lo : hi;
    }
}

// ---------------- kernel A: MFMA MLP (identical to r11; measured D_mlp = 42 us) ----------------
#define XP_STRIDE 512
#define BAND_U   5e-4f

__global__ __launch_bounds__(256, 2) void mlp_mfma_kernel(
    const float* __restrict__ z, const short* __restrict__ wfrag,
    const float* __restrict__ b1, const float* __restrict__ b2,
    const float* __restrict__ a, const float* __restrict__ lsh_b,
    short* __restrict__ xhi, short* __restrict__ xlo,
    float* __restrict__ xnorm_out, int* __restrict__ bucket_out,
    int* __restrict__ wsflag)
{
    __shared__ frag_ab LD[3072];   // 2 x 1536 units = 48 KB
    short* LDs = (short*)LD;
    const int t = threadIdx.x;
    const int l = t & 63, w = t >> 6;
    const int sw = l & 7;
    const int row0 = blockIdx.x * 128 + w * 32;
    const frag_ab* wg = (const frag_ab*)wfrag;

    frag_ab zh[2][4], zl[2][4];
#pragma unroll
    for (int rg = 0; rg < 2; ++rg)
#pragma unroll
        for (int ks = 0; ks < 4; ++ks) {
            const float* src = z + (size_t)(row0 + rg * 16 + (l & 15)) * LATENT
                             + ks * 32 + ((l >> 4) << 3);
            const float4 p0 = *(const float4*)src;
            const float4 p1 = *(const float4*)(src + 4);
            const float v[8] = {p0.x, p0.y, p0.z, p0.w, p1.x, p1.y, p1.z, p1.w};
#pragma unroll
            for (int e = 0; e < 8; ++e) {
                const short h = bf16h(v[e]);
                zh[rg][ks][e] = h;
                zl[rg][ks][e] = bf16h(v[e] - bf16tof(h));
            }
        }

    f32x4 acc2[2][4];
#pragma unroll
    for (int rg = 0; rg < 2; ++rg)
#pragma unroll
        for (int ot = 0; ot < 4; ++ot) acc2[rg][ot] = (f32x4){0.f, 0.f, 0.f, 0.f};

#pragma unroll
    for (int i = 0; i < 6; ++i)
        __builtin_amdgcn_global_load_lds(
            (const __attribute__((address_space(1))) void*)(wg + (w * 6 + i) * 64 + l),
            (__attribute__((address_space(3))) void*)(&LD[(w * 6 + i) * 64]),
            16, 0, 0);
    __syncthreads();

#pragma unroll 1
    for (int c = 0; c < 16; ++c) {
        const int pb = (c & 1) * 1536;
        const int sb = 1536 - pb;
        if (c < 15) {
#pragma unroll
            for (int i = 0; i < 6; ++i)
                __builtin_amdgcn_global_load_lds(
                    (const __attribute__((address_space(1))) void*)(wg + (size_t)(c + 1) * 1536 + (w * 6 + i) * 64 + l),
                    (__attribute__((address_space(3))) void*)(&LD[sb + (w * 6 + i) * 64]),
                    16, 0, 0);
        }

        f32x4 acc1[2][2];
#pragma unroll
        for (int ct_l = 0; ct_l < 2; ++ct_l) {
            frag_ab bh[4], bl[4];
#pragma unroll
            for (int ks = 0; ks < 4; ++ks) {
                bh[ks] = LD[pb + l * 16 + ct_l * 8 + ((ks * 2) ^ sw)];
                bl[ks] = LD[pb + l * 16 + ct_l * 8 + ((ks * 2 + 1) ^ sw)];
            }
#pragma unroll
            for (int rg = 0; rg < 2; ++rg) {
                f32x4 acc = (f32x4){0.f, 0.f, 0.f, 0.f};
#pragma unroll
                for (int ks = 0; ks < 4; ++ks) {
                    acc = __builtin_amdgcn_mfma_f32_16x16x32_bf16(bh[ks], zh[rg][ks], acc, 0, 0, 0);
                    acc = __builtin_amdgcn_mfma_f32_16x16x32_bf16(bl[ks], zh[rg][ks], acc, 0, 0, 0);
                    acc = __builtin_amdgcn_mfma_f32_16x16x32_bf16(bh[ks], zl[rg][ks], acc, 0, 0, 0);
                }
                acc1[ct_l][rg] = acc;
            }
        }

        float4 b1v[2];
#pragma unroll
        for (int ct_l = 0; ct_l < 2; ++ct_l)
            b1v[ct_l] = *(const float4*)&b1[(c * 2 + ct_l) * 16 + ((l >> 4) << 2)];
        frag_ab ah2[2], al2[2];
#pragma unroll
        for (int rg = 0; rg < 2; ++rg)
#pragma unroll
            for (int e = 0; e < 8; ++e) {
                const int tile = e >> 2, r = e & 3;
                const float bb = (r == 0) ? b1v[tile].x : (r == 1) ? b1v[tile].y
                               : (r == 2) ? b1v[tile].z : b1v[tile].w;
                const float hv = fmaxf(acc1[tile][rg][r] + bb, 0.f);
                const short hh = bf16h(hv);
                ah2[rg][e] = hh;
                al2[rg][e] = bf16h(hv - bf16tof(hh));
            }

#pragma unroll
        for (int ot = 0; ot < 4; ++ot) {
            const frag_ab b2h = LD[pb + 1024 + l * 8 + ((ot * 2) ^ sw)];
            const frag_ab b2l = LD[pb + 1024 + l * 8 + ((ot * 2 + 1) ^ sw)];
#pragma unroll
            for (int rg = 0; rg < 2; ++rg) {
                acc2[rg][ot] = __builtin_amdgcn_mfma_f32_16x16x32_bf16(ah2[rg], b2h, acc2[rg][ot], 0, 0, 0);
                acc2[rg][ot] = __builtin_amdgcn_mfma_f32_16x16x32_bf16(al2[rg], b2h, acc2[rg][ot], 0, 0, 0);
                acc2[rg][ot] = __builtin_amdgcn_mfma_f32_16x16x32_bf16(ah2[rg], b2l, acc2[rg][ot], 0, 0, 0);
            }
        }
        __syncthreads();
    }

    float b2v[4], av[4];
#pragma unroll
    for (int ot = 0; ot < 4; ++ot) {
        b2v[ot] = b2[ot * 16 + (l & 15)];
        av[ot]  = a[ot * 16 + (l & 15)];
    }
    const int pbase = w * XP_STRIDE;
    int flagged = 0;
    const float lb = lsh_b[0];
#pragma unroll
    for (int rg = 0; rg < 2; ++rg)
#pragma unroll
        for (int r = 0; r < 4; ++r) {
            float sp = 0.f, np = 0.f;
            const int row_l = rg * 16 + (l >> 4) * 4 + r;
#pragma unroll
            for (int ot = 0; ot < 4; ++ot) {
                const float xv = acc2[rg][ot][r] + b2v[ot];
                sp = fmaf(xv, av[ot], sp);
                np = fmaf(xv, xv, np);
                const int col = ot * 16 + (l & 15);
                const short xh = bf16h(xv);
                LDs[(pbase + row_l * 8 + (col >> 3)) * 8 + (col & 7)] = xh;
                LDs[(pbase + 256 + row_l * 8 + (col >> 3)) * 8 + (col & 7)] = bf16h(xv - bf16tof(xh));
            }
#pragma unroll
            for (int off = 8; off >= 1; off >>= 1) {
                sp += __shfl_xor(sp, off, 16);
                np += __shfl_xor(np, off, 16);
            }
            if ((l & 15) == 0) {
                const int row = row0 + row_l;
                const float v = sp + lb;
                const float u = v * 0.25f;
                const float fl = floorf(u);
                bucket_out[row] = ((int)fl) & (NBUCKET - 1);
                xnorm_out[row] = np;
                const float fr = u - fl;
                if (fr < BAND_U || fr > 1.f - BAND_U) flagged = 1;
            }
        }
    const unsigned long long fb = __ballot(flagged != 0);
    if (l == 0) wsflag[blockIdx.x * 4 + w] = (fb != 0ull) ? 1 : 0;

    frag_ab* xhi8 = (frag_ab*)xhi;
    frag_ab* xlo8 = (frag_ab*)xlo;
#pragma unroll
    for (int j = 0; j < 4; ++j) {
        const int u = l + 64 * j;
        const size_t gidx = (size_t)(row0 + (u >> 3)) * 8 + (u & 7);
        xhi8[gidx] = LD[pbase + u];
        xlo8[gidx] = LD[pbase + 256 + u];
    }
}

// ---------------- kernel A': gated fp32 fixup ----------------
__global__ __launch_bounds__(256, 3) void mlp_fixup_kernel(
    const float* __restrict__ z, const float* __restrict__ W1,
    const float* __restrict__ b1, const float* __restrict__ W2,
    const float* __restrict__ b2, const float* __restrict__ a,
    const float* __restrict__ lsh_b, const int* __restrict__ wsflag,
    short* __restrict__ xhi, short* __restrict__ xlo,
    float* __restrict__ xnorm_out, int* __restrict__ bucket_out)
{
    if (wsflag[blockIdx.x] == 0) return;
    __shared__ float zt[ROWS_A][LATENT];
    __shared__ float ht[ROWS_A][256];
    const int t = threadIdx.x;
    const int row0 = blockIdx.x * ROWS_A;

    {
        const float4* z4 = reinterpret_cast<const float4*>(z + (size_t)row0 * LATENT);
        float4* zt4 = reinterpret_cast<float4*>(&zt[0][0]);
#pragma unroll
        for (int i = 0; i < 4; ++i) zt4[t + 256 * i] = z4[t + 256 * i];
    }
    __syncthreads();

    const int tx = t & 63, ty = t >> 6;
    const int txq = t & 31, tyq = t >> 5;

    float acc2[4][2];
#pragma unroll
    for (int i = 0; i < 4; ++i) { acc2[i][0] = 0.f; acc2[i][1] = 0.f; }

    for (int h = 0; h < 2; ++h) {
        float acc1[8][4];
#pragma unroll
        for (int i = 0; i < 8; ++i)
#pragma unroll
            for (int cc = 0; cc < 4; ++cc) acc1[i][cc] = 0.f;

        const int jbase = h * 256 + tx;
#pragma unroll 2
        for (int k = 0; k < LATENT; k += 4) {
            float wv[4][4];
#pragma unroll
            for (int kk = 0; kk < 4; ++kk)
#pragma unroll
                for (int cc = 0; cc < 4; ++cc)
                    wv[kk][cc] = W1[(size_t)(k + kk) * HIDDEN + jbase + 64 * cc];
            float4 zv[8];
#pragma unroll
            for (int i = 0; i < 8; ++i)
                zv[i] = *reinterpret_cast<const float4*>(&zt[ty * 8 + i][k]);
#pragma unroll
            for (int i = 0; i < 8; ++i)
#pragma unroll
                for (int cc = 0; cc < 4; ++cc) {
                    acc1[i][cc] = fmaf(zv[i].x, wv[0][cc], acc1[i][cc]);
                    acc1[i][cc] = fmaf(zv[i].y, wv[1][cc], acc1[i][cc]);
                    acc1[i][cc] = fmaf(zv[i].z, wv[2][cc], acc1[i][cc]);
                    acc1[i][cc] = fmaf(zv[i].w, wv[3][cc], acc1[i][cc]);
                }
        }
        float bb[4];
#pragma unroll
        for (int cc = 0; cc < 4; ++cc) bb[cc] = b1[jbase + 64 * cc];
#pragma unroll
        for (int i = 0; i < 8; ++i)
#pragma unroll
            for (int cc = 0; cc < 4; ++cc)
                ht[ty * 8 + i][tx + 64 * cc] = fmaxf(acc1[i][cc] + bb[cc], 0.f);
        __syncthreads();

#pragma unroll 2
        for (int k = 0; k < 256; k += 4) {
            float w2v[4][2];
#pragma unroll
            for (int kk = 0; kk < 4; ++kk) {
                w2v[kk][0] = W2[(size_t)(h * 256 + k + kk) * OUT_D + txq];
                w2v[kk][1] = W2[(size_t)(h * 256 + k + kk) * OUT_D + txq + 32];
            }
            float4 hv[4];
#pragma unroll
            for (int i = 0; i < 4; ++i)
                hv[i] = *reinterpret_cast<const float4*>(&ht[tyq * 4 + i][k]);
#pragma unroll
            for (int i = 0; i < 4; ++i)
#pragma unroll
                for (int cc = 0; cc < 2; ++cc) {
                    acc2[i][cc] = fmaf(hv[i].x, w2v[0][cc], acc2[i][cc]);
                    acc2[i][cc] = fmaf(hv[i].y, w2v[1][cc], acc2[i][cc]);
                    acc2[i][cc] = fmaf(hv[i].z, w2v[2][cc], acc2[i][cc]);
                    acc2[i][cc] = fmaf(hv[i].w, w2v[3][cc], acc2[i][cc]);
                }
        }
        __syncthreads();
    }

    const float bb0 = b2[txq], bb1 = b2[txq + 32];
    const float a0 = a[txq], a1 = a[txq + 32];
    const float lb = lsh_b[0];
#pragma unroll
    for (int i = 0; i < 4; ++i) {
        const int row = row0 + tyq * 4 + i;
        const float x0 = acc2[i][0] + bb0;
        const float x1 = acc2[i][1] + bb1;
        const short h0 = bf16h(x0), h1 = bf16h(x1);
        xhi[(size_t)row * OUT_D + txq]      = h0;
        xhi[(size_t)row * OUT_D + txq + 32] = h1;
        xlo[(size_t)row * OUT_D + txq]      = bf16h(x0 - bf16tof(h0));
        xlo[(size_t)row * OUT_D + txq + 32] = bf16h(x1 - bf16tof(h1));

        float sa = fmaf(x0, a0, x1 * a1);
        float sn = fmaf(x0, x0, x1 * x1);
#pragma unroll
        for (int off = 16; off >= 1; off >>= 1) {
            sa += __shfl_xor(sa, off, 32);
            sn += __shfl_xor(sn, off, 32);
        }
        if (txq == 0) {
            const float code = floorf((sa + lb) * 0.25f);
            bucket_out[row] = ((int)code) & (NBUCKET - 1);
            xnorm_out[row] = sn;
        }
    }
}

// ---------------- kernel B1: per-block histograms + zero sums ----------------
__global__ __launch_bounds__(256) void hist_kernel(
    const int* __restrict__ bucket, int* __restrict__ blockhist,
    float* __restrict__ sums)
{
    __shared__ int h[NBUCKET];
    const int t = threadIdx.x, blk = blockIdx.x;
    for (int i = t; i < NBUCKET; i += 256) h[i] = 0;
    for (int i = t; i < NBUCKET; i += 256) sums[blk * NBUCKET + i] = 0.f;
    __syncthreads();
    const int rbase = blk * 1024;
#pragma unroll
    for (int i = 0; i < 4; ++i)
        atomicAdd(&h[bucket[rbase + i * 256 + t]], 1);
    __syncthreads();
    for (int i = t; i < NBUCKET; i += 256)
        blockhist[blk * NBUCKET + i] = h[i];
}

// ---------------- kernel B2: scan (register-preloaded, no serial load chain) ----------------
__global__ __launch_bounds__(1024) void scan_kernel(
    const int* __restrict__ blockhist, int* __restrict__ base,
    int* __restrict__ blockbase)
{
    __shared__ int sc[NBUCKET];
    const int b = threadIdx.x;
    int vals[64];
#pragma unroll
    for (int blk = 0; blk < 64; ++blk) vals[blk] = blockhist[blk * NBUCKET + b];  // independent loads
    int c = 0;
#pragma unroll
    for (int blk = 0; blk < 64; ++blk) c += vals[blk];
    sc[b] = c;
    __syncthreads();
    for (int off = 1; off < NBUCKET; off <<= 1) {
        const int add = (b >= off) ? sc[b - off] : 0;
        __syncthreads();
        sc[b] += add;
        __syncthreads();
    }
    const int offset = sc[b] - c;
    base[b] = offset;
    if (b == NBUCKET - 1) base[NBUCKET] = offset + c;
    int run = offset;
#pragma unroll
    for (int blk = 0; blk < 64; ++blk) {
        blockbase[blk * NBUCKET + b] = run;
        run += vals[blk];
    }
}

// ---------------- kernel B3: scatter ----------------
__global__ __launch_bounds__(256) void scatter_kernel(
    const int* __restrict__ bucket, const int* __restrict__ blockbase,
    int* __restrict__ order)
{
    __shared__ int lcur[NBUCKET];
    const int t = threadIdx.x, blk = blockIdx.x;
    for (int i = t; i < NBUCKET; i += 256) lcur[i] = 0;
    __syncthreads();
    const int rbase = blk * 1024;
#pragma unroll
    for (int i = 0; i < 4; ++i) {
        const int row = rbase + i * 256 + t;
        const int bk = bucket[row];
        const int r = atomicAdd(&lcur[bk], 1);
        order[blockbase[blk * NBUCKET + bk] + r] = row;
    }
}

// ---------------- kernel B4: chunked segment sums (r11 version) ----------------
__global__ __launch_bounds__(256) void chunksum_kernel(
    const short* __restrict__ xhi, const short* __restrict__ xlo,
    const int* __restrict__ order, const int* __restrict__ bucket,
    float* __restrict__ sums)
{
    const int t = threadIdx.x, lane = t & 63, w = t >> 6;
    const int c = blockIdx.x * 4 + w;
    const int i0 = c * 64;
    const int ordv = order[i0 + lane];
    const int bktv = bucket[ordv];
    float acc = 0.f;
    int cur = __shfl(bktv, 0, 64);
#pragma unroll 8
    for (int j = 0; j < 64; ++j) {
        const int rb = __shfl(ordv, j, 64);
        const int bb = __shfl(bktv, j, 64);
        if (bb != cur) {
            atomicAdd(&sums[(size_t)cur * OUT_D + lane], acc);
            acc = 0.f; cur = bb;
        }
        acc += bf16tof(xhi[(size_t)rb * OUT_D + lane])
             + bf16tof(xlo[(size_t)rb * OUT_D + lane]);
    }
    atomicAdd(&sums[(size_t)cur * OUT_D + lane], acc);
}

// ---------------- kernel B5: means, mnorm, packed B-fragments ----------------
__global__ __launch_bounds__(64) void means_kernel(
    const float* __restrict__ sums, const int* __restrict__ base,
    float* __restrict__ means_out, float* __restrict__ mnorm,
    short* __restrict__ bfrag)
{
    const int b = blockIdx.x;
    const int k = threadIdx.x;
    const int cnt = base[b + 1] - base[b];
    const float m = sums[b * OUT_D + k] / fmaxf((float)cnt, 1.0f);
    means_out[b * OUT_D + k] = m;

    const short mh = bf16h(m);
    const short ml = bf16h(m - bf16tof(mh));
    const int tile = b >> 4, col = b & 15;
    const int lane = ((k & 31) >> 3) * 16 + col;
    const int f = (k >> 5) * 2;
    const size_t idx = ((size_t)(tile * 64 + lane) * 4 + f) * 8 + (k & 7);
    bfrag[idx] = mh;
    bfrag[idx + 8] = ml;

    float s = m * m;
#pragma unroll
    for (int off = 32; off >= 1; off >>= 1) s += __shfl_xor(s, off, 64);
    if (k == 0) mnorm[b] = s;
}

// ---------------- kernel C: q_s, two-pass recompute (no q-state registers) ----------------
// Pass A: accumulate row-sums only. Pass B: recompute q, store normalized in-loop.
__global__ __launch_bounds__(256, 3) void q_kernel(
    const short* __restrict__ xhi, const short* __restrict__ xlo,
    const float* __restrict__ xnorm, const short* __restrict__ bfrag,
    const float* __restrict__ mnorm, float* __restrict__ q_out)
{
    __shared__ float rs_lds[4][2][16];
    const int t = threadIdx.x;
    const int l = t & 63;
    const int w = t >> 6;
    const int row0 = blockIdx.x * 32;
    const int lrow = (l >> 4) * 4;
    const int lcol = l & 15;

    const frag_ab* xh8 = reinterpret_cast<const frag_ab*>(xhi);
    const frag_ab* xl8 = reinterpret_cast<const frag_ab*>(xlo);
    frag_ab ah[2][2], al[2][2];
#pragma unroll
    for (int s = 0; s < 2; ++s)
#pragma unroll
        for (int kh = 0; kh < 2; ++kh) {
            const size_t idx8 = (size_t)(row0 + s * 16 + lcol) * 8 + kh * 4 + (l >> 4);
            ah[s][kh] = xh8[idx8];
            al[s][kh] = xl8[idx8];
        }

    float xn[2][4];
#pragma unroll
    for (int s = 0; s < 2; ++s)
#pragma unroll
        for (int r = 0; r < 4; ++r) xn[s][r] = xnorm[row0 + s * 16 + lrow + r];

    const frag_ab* bf8 = reinterpret_cast<const frag_ab*>(bfrag);
    float rsp[2][4] = {{0.f,0.f,0.f,0.f},{0.f,0.f,0.f,0.f}};

    // ---- pass A: row sums ----
#pragma unroll
    for (int j = 0; j < 16; ++j) {
        const int bt = w + 4 * j;
        const size_t bb = (size_t)(bt * 64 + l) * 4;
        const frag_ab b0h = bf8[bb + 0];
        const frag_ab b0l = bf8[bb + 1];
        const frag_ab b1h = bf8[bb + 2];
        const frag_ab b1l = bf8[bb + 3];
        const float mn = mnorm[bt * 16 + lcol];

#pragma unroll
        for (int s = 0; s < 2; ++s) {
            f32x4 acc = {0.f, 0.f, 0.f, 0.f};
            acc = __builtin_amdgcn_mfma_f32_16x16x32_bf16(ah[s][0], b0h, acc, 0, 0, 0);
            acc = __builtin_amdgcn_mfma_f32_16x16x32_bf16(ah[s][1], b1h, acc, 0, 0, 0);
            acc = __builtin_amdgcn_mfma_f32_16x16x32_bf16(ah[s][0], b0l, acc, 0, 0, 0);
            acc = __builtin_amdgcn_mfma_f32_16x16x32_bf16(ah[s][1], b1l, acc, 0, 0, 0);
            acc = __builtin_amdgcn_mfma_f32_16x16x32_bf16(al[s][0], b0h, acc, 0, 0, 0);
            acc = __builtin_amdgcn_mfma_f32_16x16x32_bf16(al[s][1], b1h, acc, 0, 0, 0);
#pragma unroll
            for (int r = 0; r < 4; ++r) {
                const float d2 = fmaxf(fmaf(-2.f, acc[r], xn[s][r] + mn), 0.f);
                rsp[s][r] += __builtin_amdgcn_rcpf(1.f + d2);
            }
        }
    }

#pragma unroll
    for (int off = 8; off >= 1; off >>= 1)
#pragma unroll
        for (int s = 0; s < 2; ++s)
#pragma unroll
            for (int r = 0; r < 4; ++r) rsp[s][r] += __shfl_xor(rsp[s][r], off, 16);
    if (lcol == 0) {
#pragma unroll
        for (int s = 0; s < 2; ++s)
#pragma unroll
            for (int r = 0; r < 4; ++r) rs_lds[w][s][lrow + r] = rsp[s][r];
    }
    __syncthreads();

    float inv[2][4];
#pragma unroll
    for (int s = 0; s < 2; ++s)
#pragma unroll
        for (int r = 0; r < 4; ++r) {
            const float tot = rs_lds[0][s][lrow + r] + rs_lds[1][s][lrow + r]
                            + rs_lds[2][s][lrow + r] + rs_lds[3][s][lrow + r];
            inv[s][r] = __builtin_amdgcn_rcpf(tot);
        }

    // ---- pass B: recompute + normalized store (stores spread over the loop) ----
#pragma unroll
    for (int j = 0; j < 16; ++j) {
        const int bt = w + 4 * j;
        const size_t bb = (size_t)(bt * 64 + l) * 4;
        const frag_ab b0h = bf8[bb + 0];
        const frag_ab b0l = bf8[bb + 1];
        const frag_ab b1h = bf8[bb + 2];
        const frag_ab b1l = bf8[bb + 3];
        const float mn = mnorm[bt * 16 + lcol];
        const int col = bt * 16 + lcol;

#pragma unroll
        for (int s = 0; s < 2; ++s) {
            f32x4 acc = {0.f, 0.f, 0.f, 0.f};
            acc = __builtin_amdgcn_mfma_f32_16x16x32_bf16(ah[s][0], b0h, acc, 0, 0, 0);
            acc = __builtin_amdgcn_mfma_f32_16x16x32_bf16(ah[s][1], b1h, acc, 0, 0, 0);
            acc = __builtin_amdgcn_mfma_f32_16x16x32_bf16(ah[s][0], b0l, acc, 0, 0, 0);
            acc = __builtin_amdgcn_mfma_f32_16x16x32_bf16(ah[s][1], b1l, acc, 0, 0, 0);
            acc = __builtin_amdgcn_mfma_f32_16x16x32_bf16(al[s][0], b0h, acc, 0, 0, 0);
            acc = __builtin_amdgcn_mfma_f32_16x16x32_bf16(al[s][1], b1h, acc, 0, 0, 0);

            const size_t rb = (size_t)(row0 + s * 16 + lrow) * NBUCKET + col;
#pragma unroll
            for (int r = 0; r < 4; ++r) {
                const float d2 = fmaxf(fmaf(-2.f, acc[r], xn[s][r] + mn), 0.f);
                const float qq = __builtin_amdgcn_rcpf(1.f + d2);
                __builtin_nontemporal_store(qq * inv[s][r], &q_out[rb + (size_t)r * NBUCKET]);
            }
        }
    }
}

extern "C" void kernel_launch(void* const* d_in, const int* in_sizes, int n_in,
                              void* d_out, int out_size, void* d_ws, size_t ws_size,
                              hipStream_t stream) {
    const float* z    = (const float*)d_in[0];
    const float* W1   = (const float*)d_in[1];
    const float* b1   = (const float*)d_in[2];
    const float* W2   = (const float*)d_in[3];
    const float* b2   = (const float*)d_in[4];
    const float* a    = (const float*)d_in[5];
    const float* lshb = (const float*)d_in[6];

    float* q_out     = (float*)d_out;
    float* means_out = q_out + (size_t)N_PTS * NBUCKET;   // outputs: (q_s, means)

    char* ws = (char*)d_ws;
    short* xhi    = (short*)ws;                               // N*64 = 8 MB
    short* xlo    = xhi + (size_t)N_PTS * OUT_D;              // 8 MB
    short* bfrag  = xlo + (size_t)N_PTS * OUT_D;              // 256 KB
    short* wfrag  = bfrag + (size_t)64 * 64 * 4 * 8;          // 384 KB
    float* xnorm  = (float*)(wfrag + (size_t)16 * 1536 * 8);  // N
    float* mnorm  = xnorm + N_PTS;                            // B
    float* sums   = mnorm + NBUCKET;                          // B*64
    int*   bucket = (int*)(sums + (size_t)NBUCKET * OUT_D);   // N
    int*   order  = bucket + N_PTS;                           // N
    int*   blockhist = order + N_PTS;                         // 64*1024
    int*   blockbase = blockhist + 64 * NBUCKET;              // 64*1024
    int*   base      = blockbase + 64 * NBUCKET;              // 1025
    int*   wsflag    = base + NBUCKET + 1;                    // 2048

    prep_weights<<<96, 256, 0, stream>>>(W1, W2, wfrag);
    mlp_mfma_kernel<<<N_PTS / 128, 256, 0, stream>>>(z, wfrag, b1, b2, a, lshb,
                                                     xhi, xlo, xnorm, bucket, wsflag);
    mlp_fixup_kernel<<<N_PTS / ROWS_A, 256, 0, stream>>>(z, W1, b1, W2, b2, a, lshb, wsflag,
                                                         xhi, xlo, xnorm, bucket);
    hist_kernel<<<64, 256, 0, stream>>>(bucket, blockhist, sums);
    scan_kernel<<<1, 1024, 0, stream>>>(blockhist, base, blockbase);
    scatter_kernel<<<64, 256, 0, stream>>>(bucket, blockbase, order);
    chunksum_kernel<<<256, 256, 0, stream>>>(xhi, xlo, order, bucket, sums);
    means_kernel<<<NBUCKET, 64, 0, stream>>>(sums, base, means_out, mnorm, bfrag);
    q_kernel<<<N_PTS / 32, 256, 0, stream>>>(xhi, xlo, xnorm, bfrag, mnorm, q_out);
}

// Round 16
// 294.270 us; speedup vs baseline: 1.0024x; 1.0024x over previous
//
#include <hip/hip_runtime.h>
#include <hip/hip_bf16.h>

#define N_PTS   65536
#define LATENT  128
#define HIDDEN  512
#define OUT_D   64
#define NBUCKET 1024
#define ROWS_A  32

typedef __attribute__((ext_vector_type(8))) short frag_ab;   // 8 bf16
typedef __attribute__((ext_vector_type(4))) float f32x4;

__device__ __forceinline__ short bf16h(float f) {
    union { float f; unsigned u; } c; c.f = f;
    const unsigned r = (c.u + 0x7FFFu + ((c.u >> 16) & 1u)) >> 16;  // RNE
    return (short)r;
}
__device__ __forceinline__ float bf16tof(short s) {
    union { unsigned u; float f; } c; c.u = ((unsigned)(unsigned short)s) << 16;
    return c.f;
}

// ---------------- kernel P: pack W1/W2 -> per-chunk swizzled-linear frag stream ----------------
__global__ __launch_bounds__(256) void prep_weights(
    const float* __restrict__ W1, const float* __restrict__ W2,
    short* __restrict__ wfrag)
{
    const int tid = blockIdx.x * 256 + threadIdx.x;   // 0..24575
    const int c = tid / 1536;
    const int u = tid % 1536;
    frag_ab hi, lo;
    if (u < 1024) {
        const int l = u >> 4, slot = u & 15;
        const int j = slot ^ (l & 7);
        const int ct = j >> 3, ks = (j >> 1) & 3, hl = j & 1;
        const int n = (c * 2 + ct) * 16 + (l & 15);
        const int k0 = ks * 32 + ((l >> 4) << 3);
#pragma unroll
        for (int e = 0; e < 8; ++e) {
            const float wv = W1[(size_t)(k0 + e) * HIDDEN + n];
            const short h = bf16h(wv);
            hi[e] = h;
            lo[e] = bf16h(wv - bf16tof(h));
        }
        ((frag_ab*)wfrag)[(size_t)c * 1536 + u] = hl ? lo : hi;
    } else {
        const int u2 = u - 1024;
        const int l = u2 >> 3, slot = u2 & 7;
        const int j = slot ^ (l & 7);
        const int ot = j >> 1, hl = j & 1;
        const int n = ot * 16 + (l & 15);
#pragma unroll
        for (int e = 0; e < 8; ++e) {
            const int k = c * 32 + ((e >> 2) << 4) + ((l >> 4) << 2) + (e & 3);
            const float wv = W2[(size_t)k * OUT_D + n];
            const short h = bf16h(wv);
            hi[e] = h;
            lo[e] = bf16h(wv - bf16tof(h));
        }
        ((frag_ab*)wfrag)[(size_t)c * 1536 + u] = hl ? lo : hi;
    }
}

// ---------------- kernel A: MFMA MLP (identical to r11; measured D_mlp = 42 us) ----------------
#define XP_STRIDE 512
#define BAND_U   5e-4f

__global__ __launch_bounds__(256, 2) void mlp_mfma_kernel(
    const float* __restrict__ z, const short* __restrict__ wfrag,
    const float* __restrict__ b1, const float* __restrict__ b2,
    const float* __restrict__ a, const float* __restrict__ lsh_b,
    short* __restrict__ xhi, short* __restrict__ xlo,
    float* __restrict__ xnorm_out, int* __restrict__ bucket_out,
    int* __restrict__ wsflag)
{
    __shared__ frag_ab LD[3072];   // 2 x 1536 units = 48 KB
    short* LDs = (short*)LD;
    const int t = threadIdx.x;
    const int l = t & 63, w = t >> 6;
    const int sw = l & 7;
    const int row0 = blockIdx.x * 128 + w * 32;
    const frag_ab* wg = (const frag_ab*)wfrag;

    frag_ab zh[2][4], zl[2][4];
#pragma unroll
    for (int rg = 0; rg < 2; ++rg)
#pragma unroll
        for (int ks = 0; ks < 4; ++ks) {
            const float* src = z + (size_t)(row0 + rg * 16 + (l & 15)) * LATENT
                             + ks * 32 + ((l >> 4) << 3);
            const float4 p0 = *(const float4*)src;
            const float4 p1 = *(const float4*)(src + 4);
            const float v[8] = {p0.x, p0.y, p0.z, p0.w, p1.x, p1.y, p1.z, p1.w};
#pragma unroll
            for (int e = 0; e < 8; ++e) {
                const short h = bf16h(v[e]);
                zh[rg][ks][e] = h;
                zl[rg][ks][e] = bf16h(v[e] - bf16tof(h));
            }
        }

    f32x4 acc2[2][4];
#pragma unroll
    for (int rg = 0; rg < 2; ++rg)
#pragma unroll
        for (int ot = 0; ot < 4; ++ot) acc2[rg][ot] = (f32x4){0.f, 0.f, 0.f, 0.f};

#pragma unroll
    for (int i = 0; i < 6; ++i)
        __builtin_amdgcn_global_load_lds(
            (const __attribute__((address_space(1))) void*)(wg + (w * 6 + i) * 64 + l),
            (__attribute__((address_space(3))) void*)(&LD[(w * 6 + i) * 64]),
            16, 0, 0);
    __syncthreads();

#pragma unroll 1
    for (int c = 0; c < 16; ++c) {
        const int pb = (c & 1) * 1536;
        const int sb = 1536 - pb;
        if (c < 15) {
#pragma unroll
            for (int i = 0; i < 6; ++i)
                __builtin_amdgcn_global_load_lds(
                    (const __attribute__((address_space(1))) void*)(wg + (size_t)(c + 1) * 1536 + (w * 6 + i) * 64 + l),
                    (__attribute__((address_space(3))) void*)(&LD[sb + (w * 6 + i) * 64]),
                    16, 0, 0);
        }

        f32x4 acc1[2][2];
#pragma unroll
        for (int ct_l = 0; ct_l < 2; ++ct_l) {
            frag_ab bh[4], bl[4];
#pragma unroll
            for (int ks = 0; ks < 4; ++ks) {
                bh[ks] = LD[pb + l * 16 + ct_l * 8 + ((ks * 2) ^ sw)];
                bl[ks] = LD[pb + l * 16 + ct_l * 8 + ((ks * 2 + 1) ^ sw)];
            }
#pragma unroll
            for (int rg = 0; rg < 2; ++rg) {
                f32x4 acc = (f32x4){0.f, 0.f, 0.f, 0.f};
#pragma unroll
                for (int ks = 0; ks < 4; ++ks) {
                    acc = __builtin_amdgcn_mfma_f32_16x16x32_bf16(bh[ks], zh[rg][ks], acc, 0, 0, 0);
                    acc = __builtin_amdgcn_mfma_f32_16x16x32_bf16(bl[ks], zh[rg][ks], acc, 0, 0, 0);
                    acc = __builtin_amdgcn_mfma_f32_16x16x32_bf16(bh[ks], zl[rg][ks], acc, 0, 0, 0);
                }
                acc1[ct_l][rg] = acc;
            }
        }

        float4 b1v[2];
#pragma unroll
        for (int ct_l = 0; ct_l < 2; ++ct_l)
            b1v[ct_l] = *(const float4*)&b1[(c * 2 + ct_l) * 16 + ((l >> 4) << 2)];
        frag_ab ah2[2], al2[2];
#pragma unroll
        for (int rg = 0; rg < 2; ++rg)
#pragma unroll
            for (int e = 0; e < 8; ++e) {
                const int tile = e >> 2, r = e & 3;
                const float bb = (r == 0) ? b1v[tile].x : (r == 1) ? b1v[tile].y
                               : (r == 2) ? b1v[tile].z : b1v[tile].w;
                const float hv = fmaxf(acc1[tile][rg][r] + bb, 0.f);
                const short hh = bf16h(hv);
                ah2[rg][e] = hh;
                al2[rg][e] = bf16h(hv - bf16tof(hh));
            }

#pragma unroll
        for (int ot = 0; ot < 4; ++ot) {
            const frag_ab b2h = LD[pb + 1024 + l * 8 + ((ot * 2) ^ sw)];
            const frag_ab b2l = LD[pb + 1024 + l * 8 + ((ot * 2 + 1) ^ sw)];
#pragma unroll
            for (int rg = 0; rg < 2; ++rg) {
                acc2[rg][ot] = __builtin_amdgcn_mfma_f32_16x16x32_bf16(ah2[rg], b2h, acc2[rg][ot], 0, 0, 0);
                acc2[rg][ot] = __builtin_amdgcn_mfma_f32_16x16x32_bf16(al2[rg], b2h, acc2[rg][ot], 0, 0, 0);
                acc2[rg][ot] = __builtin_amdgcn_mfma_f32_16x16x32_bf16(ah2[rg], b2l, acc2[rg][ot], 0, 0, 0);
            }
        }
        __syncthreads();
    }

    float b2v[4], av[4];
#pragma unroll
    for (int ot = 0; ot < 4; ++ot) {
        b2v[ot] = b2[ot * 16 + (l & 15)];
        av[ot]  = a[ot * 16 + (l & 15)];
    }
    const int pbase = w * XP_STRIDE;
    int flagged = 0;
    const float lb = lsh_b[0];
#pragma unroll
    for (int rg = 0; rg < 2; ++rg)
#pragma unroll
        for (int r = 0; r < 4; ++r) {
            float sp = 0.f, np = 0.f;
            const int row_l = rg * 16 + (l >> 4) * 4 + r;
#pragma unroll
            for (int ot = 0; ot < 4; ++ot) {
                const float xv = acc2[rg][ot][r] + b2v[ot];
                sp = fmaf(xv, av[ot], sp);
                np = fmaf(xv, xv, np);
                const int col = ot * 16 + (l & 15);
                const short xh = bf16h(xv);
                LDs[(pbase + row_l * 8 + (col >> 3)) * 8 + (col & 7)] = xh;
                LDs[(pbase + 256 + row_l * 8 + (col >> 3)) * 8 + (col & 7)] = bf16h(xv - bf16tof(xh));
            }
#pragma unroll
            for (int off = 8; off >= 1; off >>= 1) {
                sp += __shfl_xor(sp, off, 16);
                np += __shfl_xor(np, off, 16);
            }
            if ((l & 15) == 0) {
                const int row = row0 + row_l;
                const float v = sp + lb;
                const float u = v * 0.25f;
                const float fl = floorf(u);
                bucket_out[row] = ((int)fl) & (NBUCKET - 1);
                xnorm_out[row] = np;
                const float fr = u - fl;
                if (fr < BAND_U || fr > 1.f - BAND_U) flagged = 1;
            }
        }
    const unsigned long long fb = __ballot(flagged != 0);
    if (l == 0) wsflag[blockIdx.x * 4 + w] = (fb != 0ull) ? 1 : 0;

    frag_ab* xhi8 = (frag_ab*)xhi;
    frag_ab* xlo8 = (frag_ab*)xlo;
#pragma unroll
    for (int j = 0; j < 4; ++j) {
        const int u = l + 64 * j;
        const size_t gidx = (size_t)(row0 + (u >> 3)) * 8 + (u & 7);
        xhi8[gidx] = LD[pbase + u];
        xlo8[gidx] = LD[pbase + 256 + u];
    }
}

// ---------------- kernel A': gated fp32 fixup ----------------
__global__ __launch_bounds__(256, 3) void mlp_fixup_kernel(
    const float* __restrict__ z, const float* __restrict__ W1,
    const float* __restrict__ b1, const float* __restrict__ W2,
    const float* __restrict__ b2, const float* __restrict__ a,
    const float* __restrict__ lsh_b, const int* __restrict__ wsflag,
    short* __restrict__ xhi, short* __restrict__ xlo,
    float* __restrict__ xnorm_out, int* __restrict__ bucket_out)
{
    if (wsflag[blockIdx.x] == 0) return;
    __shared__ float zt[ROWS_A][LATENT];
    __shared__ float ht[ROWS_A][256];
    const int t = threadIdx.x;
    const int row0 = blockIdx.x * ROWS_A;

    {
        const float4* z4 = reinterpret_cast<const float4*>(z + (size_t)row0 * LATENT);
        float4* zt4 = reinterpret_cast<float4*>(&zt[0][0]);
#pragma unroll
        for (int i = 0; i < 4; ++i) zt4[t + 256 * i] = z4[t + 256 * i];
    }
    __syncthreads();

    const int tx = t & 63, ty = t >> 6;
    const int txq = t & 31, tyq = t >> 5;

    float acc2[4][2];
#pragma unroll
    for (int i = 0; i < 4; ++i) { acc2[i][0] = 0.f; acc2[i][1] = 0.f; }

    for (int h = 0; h < 2; ++h) {
        float acc1[8][4];
#pragma unroll
        for (int i = 0; i < 8; ++i)
#pragma unroll
            for (int cc = 0; cc < 4; ++cc) acc1[i][cc] = 0.f;

        const int jbase = h * 256 + tx;
#pragma unroll 2
        for (int k = 0; k < LATENT; k += 4) {
            float wv[4][4];
#pragma unroll
            for (int kk = 0; kk < 4; ++kk)
#pragma unroll
                for (int cc = 0; cc < 4; ++cc)
                    wv[kk][cc] = W1[(size_t)(k + kk) * HIDDEN + jbase + 64 * cc];
            float4 zv[8];
#pragma unroll
            for (int i = 0; i < 8; ++i)
                zv[i] = *reinterpret_cast<const float4*>(&zt[ty * 8 + i][k]);
#pragma unroll
            for (int i = 0; i < 8; ++i)
#pragma unroll
                for (int cc = 0; cc < 4; ++cc) {
                    acc1[i][cc] = fmaf(zv[i].x, wv[0][cc], acc1[i][cc]);
                    acc1[i][cc] = fmaf(zv[i].y, wv[1][cc], acc1[i][cc]);
                    acc1[i][cc] = fmaf(zv[i].z, wv[2][cc], acc1[i][cc]);
                    acc1[i][cc] = fmaf(zv[i].w, wv[3][cc], acc1[i][cc]);
                }
        }
        float bb[4];
#pragma unroll
        for (int cc = 0; cc < 4; ++cc) bb[cc] = b1[jbase + 64 * cc];
#pragma unroll
        for (int i = 0; i < 8; ++i)
#pragma unroll
            for (int cc = 0; cc < 4; ++cc)
                ht[ty * 8 + i][tx + 64 * cc] = fmaxf(acc1[i][cc] + bb[cc], 0.f);
        __syncthreads();

#pragma unroll 2
        for (int k = 0; k < 256; k += 4) {
            float w2v[4][2];
#pragma unroll
            for (int kk = 0; kk < 4; ++kk) {
                w2v[kk][0] = W2[(size_t)(h * 256 + k + kk) * OUT_D + txq];
                w2v[kk][1] = W2[(size_t)(h * 256 + k + kk) * OUT_D + txq + 32];
            }
            float4 hv[4];
#pragma unroll
            for (int i = 0; i < 4; ++i)
                hv[i] = *reinterpret_cast<const float4*>(&ht[tyq * 4 + i][k]);
#pragma unroll
            for (int i = 0; i < 4; ++i)
#pragma unroll
                for (int cc = 0; cc < 2; ++cc) {
                    acc2[i][cc] = fmaf(hv[i].x, w2v[0][cc], acc2[i][cc]);
                    acc2[i][cc] = fmaf(hv[i].y, w2v[1][cc], acc2[i][cc]);
                    acc2[i][cc] = fmaf(hv[i].z, w2v[2][cc], acc2[i][cc]);
                    acc2[i][cc] = fmaf(hv[i].w, w2v[3][cc], acc2[i][cc]);
                }
        }
        __syncthreads();
    }

    const float bb0 = b2[txq], bb1 = b2[txq + 32];
    const float a0 = a[txq], a1 = a[txq + 32];
    const float lb = lsh_b[0];
#pragma unroll
    for (int i = 0; i < 4; ++i) {
        const int row = row0 + tyq * 4 + i;
        const float x0 = acc2[i][0] + bb0;
        const float x1 = acc2[i][1] + bb1;
        const short h0 = bf16h(x0), h1 = bf16h(x1);
        xhi[(size_t)row * OUT_D + txq]      = h0;
        xhi[(size_t)row * OUT_D + txq + 32] = h1;
        xlo[(size_t)row * OUT_D + txq]      = bf16h(x0 - bf16tof(h0));
        xlo[(size_t)row * OUT_D + txq + 32] = bf16h(x1 - bf16tof(h1));

        float sa = fmaf(x0, a0, x1 * a1);
        float sn = fmaf(x0, x0, x1 * x1);
#pragma unroll
        for (int off = 16; off >= 1; off >>= 1) {
            sa += __shfl_xor(sa, off, 32);
            sn += __shfl_xor(sn, off, 32);
        }
        if (txq == 0) {
            const float code = floorf((sa + lb) * 0.25f);
            bucket_out[row] = ((int)code) & (NBUCKET - 1);
            xnorm_out[row] = sn;
        }
    }
}

// ---------------- kernel B1: per-block histograms + zero sums ----------------
__global__ __launch_bounds__(256) void hist_kernel(
    const int* __restrict__ bucket, int* __restrict__ blockhist,
    float* __restrict__ sums)
{
    __shared__ int h[NBUCKET];
    const int t = threadIdx.x, blk = blockIdx.x;
    for (int i = t; i < NBUCKET; i += 256) h[i] = 0;
    for (int i = t; i < NBUCKET; i += 256) sums[blk * NBUCKET + i] = 0.f;
    __syncthreads();
    const int rbase = blk * 1024;
#pragma unroll
    for (int i = 0; i < 4; ++i)
        atomicAdd(&h[bucket[rbase + i * 256 + t]], 1);
    __syncthreads();
    for (int i = t; i < NBUCKET; i += 256)
        blockhist[blk * NBUCKET + i] = h[i];
}

// ---------------- kernel B2: scan (register-preloaded, no serial load chain) ----------------
__global__ __launch_bounds__(1024) void scan_kernel(
    const int* __restrict__ blockhist, int* __restrict__ base,
    int* __restrict__ blockbase)
{
    __shared__ int sc[NBUCKET];
    const int b = threadIdx.x;
    int vals[64];
#pragma unroll
    for (int blk = 0; blk < 64; ++blk) vals[blk] = blockhist[blk * NBUCKET + b];  // independent loads
    int c = 0;
#pragma unroll
    for (int blk = 0; blk < 64; ++blk) c += vals[blk];
    sc[b] = c;
    __syncthreads();
    for (int off = 1; off < NBUCKET; off <<= 1) {
        const int add = (b >= off) ? sc[b - off] : 0;
        __syncthreads();
        sc[b] += add;
        __syncthreads();
    }
    const int offset = sc[b] - c;
    base[b] = offset;
    if (b == NBUCKET - 1) base[NBUCKET] = offset + c;
    int run = offset;
#pragma unroll
    for (int blk = 0; blk < 64; ++blk) {
        blockbase[blk * NBUCKET + b] = run;
        run += vals[blk];
    }
}

// ---------------- kernel B3: scatter ----------------
__global__ __launch_bounds__(256) void scatter_kernel(
    const int* __restrict__ bucket, const int* __restrict__ blockbase,
    int* __restrict__ order)
{
    __shared__ int lcur[NBUCKET];
    const int t = threadIdx.x, blk = blockIdx.x;
    for (int i = t; i < NBUCKET; i += 256) lcur[i] = 0;
    __syncthreads();
    const int rbase = blk * 1024;
#pragma unroll
    for (int i = 0; i < 4; ++i) {
        const int row = rbase + i * 256 + t;
        const int bk = bucket[row];
        const int r = atomicAdd(&lcur[bk], 1);
        order[blockbase[blk * NBUCKET + bk] + r] = row;
    }
}

// ---------------- kernel B4: chunked segment sums (r11 version) ----------------
__global__ __launch_bounds__(256) void chunksum_kernel(
    const short* __restrict__ xhi, const short* __restrict__ xlo,
    const int* __restrict__ order, const int* __restrict__ bucket,
    float* __restrict__ sums)
{
    const int t = threadIdx.x, lane = t & 63, w = t >> 6;
    const int c = blockIdx.x * 4 + w;
    const int i0 = c * 64;
    const int ordv = order[i0 + lane];
    const int bktv = bucket[ordv];
    float acc = 0.f;
    int cur = __shfl(bktv, 0, 64);
#pragma unroll 8
    for (int j = 0; j < 64; ++j) {
        const int rb = __shfl(ordv, j, 64);
        const int bb = __shfl(bktv, j, 64);
        if (bb != cur) {
            atomicAdd(&sums[(size_t)cur * OUT_D + lane], acc);
            acc = 0.f; cur = bb;
        }
        acc += bf16tof(xhi[(size_t)rb * OUT_D + lane])
             + bf16tof(xlo[(size_t)rb * OUT_D + lane]);
    }
    atomicAdd(&sums[(size_t)cur * OUT_D + lane], acc);
}

// ---------------- kernel B5: means, mnorm, packed B-fragments ----------------
__global__ __launch_bounds__(64) void means_kernel(
    const float* __restrict__ sums, const int* __restrict__ base,
    float* __restrict__ means_out, float* __restrict__ mnorm,
    short* __restrict__ bfrag)
{
    const int b = blockIdx.x;
    const int k = threadIdx.x;
    const int cnt = base[b + 1] - base[b];
    const float m = sums[b * OUT_D + k] / fmaxf((float)cnt, 1.0f);
    means_out[b * OUT_D + k] = m;

    const short mh = bf16h(m);
    const short ml = bf16h(m - bf16tof(mh));
    const int tile = b >> 4, col = b & 15;
    const int lane = ((k & 31) >> 3) * 16 + col;
    const int f = (k >> 5) * 2;
    const size_t idx = ((size_t)(tile * 64 + lane) * 4 + f) * 8 + (k & 7);
    bfrag[idx] = mh;
    bfrag[idx + 8] = ml;

    float s = m * m;
#pragma unroll
    for (int off = 32; off >= 1; off >>= 1) s += __shfl_xor(s, off, 64);
    if (k == 0) mnorm[b] = s;
}

// ---------------- kernel C: q_s, two-pass recompute (no q-state registers) ----------------
// Pass A: accumulate row-sums only. Pass B: recompute q, store normalized in-loop.
__global__ __launch_bounds__(256, 3) void q_kernel(
    const short* __restrict__ xhi, const short* __restrict__ xlo,
    const float* __restrict__ xnorm, const short* __restrict__ bfrag,
    const float* __restrict__ mnorm, float* __restrict__ q_out)
{
    __shared__ float rs_lds[4][2][16];
    const int t = threadIdx.x;
    const int l = t & 63;
    const int w = t >> 6;
    const int row0 = blockIdx.x * 32;
    const int lrow = (l >> 4) * 4;
    const int lcol = l & 15;

    const frag_ab* xh8 = reinterpret_cast<const frag_ab*>(xhi);
    const frag_ab* xl8 = reinterpret_cast<const frag_ab*>(xlo);
    frag_ab ah[2][2], al[2][2];
#pragma unroll
    for (int s = 0; s < 2; ++s)
#pragma unroll
        for (int kh = 0; kh < 2; ++kh) {
            const size_t idx8 = (size_t)(row0 + s * 16 + lcol) * 8 + kh * 4 + (l >> 4);
            ah[s][kh] = xh8[idx8];
            al[s][kh] = xl8[idx8];
        }

    float xn[2][4];
#pragma unroll
    for (int s = 0; s < 2; ++s)
#pragma unroll
        for (int r = 0; r < 4; ++r) xn[s][r] = xnorm[row0 + s * 16 + lrow + r];

    const frag_ab* bf8 = reinterpret_cast<const frag_ab*>(bfrag);
    float rsp[2][4] = {{0.f,0.f,0.f,0.f},{0.f,0.f,0.f,0.f}};

    // ---- pass A: row sums ----
#pragma unroll
    for (int j = 0; j < 16; ++j) {
        const int bt = w + 4 * j;
        const size_t bb = (size_t)(bt * 64 + l) * 4;
        const frag_ab b0h = bf8[bb + 0];
        const frag_ab b0l = bf8[bb + 1];
        const frag_ab b1h = bf8[bb + 2];
        const frag_ab b1l = bf8[bb + 3];
        const float mn = mnorm[bt * 16 + lcol];

#pragma unroll
        for (int s = 0; s < 2; ++s) {
            f32x4 acc = {0.f, 0.f, 0.f, 0.f};
            acc = __builtin_amdgcn_mfma_f32_16x16x32_bf16(ah[s][0], b0h, acc, 0, 0, 0);
            acc = __builtin_amdgcn_mfma_f32_16x16x32_bf16(ah[s][1], b1h, acc, 0, 0, 0);
            acc = __builtin_amdgcn_mfma_f32_16x16x32_bf16(ah[s][0], b0l, acc, 0, 0, 0);
            acc = __builtin_amdgcn_mfma_f32_16x16x32_bf16(ah[s][1], b1l, acc, 0, 0, 0);
            acc = __builtin_amdgcn_mfma_f32_16x16x32_bf16(al[s][0], b0h, acc, 0, 0, 0);
            acc = __builtin_amdgcn_mfma_f32_16x16x32_bf16(al[s][1], b1h, acc, 0, 0, 0);
#pragma unroll
            for (int r = 0; r < 4; ++r) {
                const float d2 = fmaxf(fmaf(-2.f, acc[r], xn[s][r] + mn), 0.f);
                rsp[s][r] += __builtin_amdgcn_rcpf(1.f + d2);
            }
        }
    }

#pragma unroll
    for (int off = 8; off >= 1; off >>= 1)
#pragma unroll
        for (int s = 0; s < 2; ++s)
#pragma unroll
            for (int r = 0; r < 4; ++r) rsp[s][r] += __shfl_xor(rsp[s][r], off, 16);
    if (lcol == 0) {
#pragma unroll
        for (int s = 0; s < 2; ++s)
#pragma unroll
            for (int r = 0; r < 4; ++r) rs_lds[w][s][lrow + r] = rsp[s][r];
    }
    __syncthreads();

    float inv[2][4];
#pragma unroll
    for (int s = 0; s < 2; ++s)
#pragma unroll
        for (int r = 0; r < 4; ++r) {
            const float tot = rs_lds[0][s][lrow + r] + rs_lds[1][s][lrow + r]
                            + rs_lds[2][s][lrow + r] + rs_lds[3][s][lrow + r];
            inv[s][r] = __builtin_amdgcn_rcpf(tot);
        }

    // ---- pass B: recompute + normalized store (stores spread over the loop) ----
#pragma unroll
    for (int j = 0; j < 16; ++j) {
        const int bt = w + 4 * j;
        const size_t bb = (size_t)(bt * 64 + l) * 4;
        const frag_ab b0h = bf8[bb + 0];
        const frag_ab b0l = bf8[bb + 1];
        const frag_ab b1h = bf8[bb + 2];
        const frag_ab b1l = bf8[bb + 3];
        const float mn = mnorm[bt * 16 + lcol];
        const int col = bt * 16 + lcol;

#pragma unroll
        for (int s = 0; s < 2; ++s) {
            f32x4 acc = {0.f, 0.f, 0.f, 0.f};
            acc = __builtin_amdgcn_mfma_f32_16x16x32_bf16(ah[s][0], b0h, acc, 0, 0, 0);
            acc = __builtin_amdgcn_mfma_f32_16x16x32_bf16(ah[s][1], b1h, acc, 0, 0, 0);
            acc = __builtin_amdgcn_mfma_f32_16x16x32_bf16(ah[s][0], b0l, acc, 0, 0, 0);
            acc = __builtin_amdgcn_mfma_f32_16x16x32_bf16(ah[s][1], b1l, acc, 0, 0, 0);
            acc = __builtin_amdgcn_mfma_f32_16x16x32_bf16(al[s][0], b0h, acc, 0, 0, 0);
            acc = __builtin_amdgcn_mfma_f32_16x16x32_bf16(al[s][1], b1h, acc, 0, 0, 0);

            const size_t rb = (size_t)(row0 + s * 16 + lrow) * NBUCKET + col;
#pragma unroll
            for (int r = 0; r < 4; ++r) {
                const float d2 = fmaxf(fmaf(-2.f, acc[r], xn[s][r] + mn), 0.f);
                const float qq = __builtin_amdgcn_rcpf(1.f + d2);
                __builtin_nontemporal_store(qq * inv[s][r], &q_out[rb + (size_t)r * NBUCKET]);
            }
        }
    }
}

extern "C" void kernel_launch(void* const* d_in, const int* in_sizes, int n_in,
                              void* d_out, int out_size, void* d_ws, size_t ws_size,
                              hipStream_t stream) {
    const float* z    = (const float*)d_in[0];
    const float* W1   = (const float*)d_in[1];
    const float* b1   = (const float*)d_in[2];
    const float* W2   = (const float*)d_in[3];
    const float* b2   = (const float*)d_in[4];
    const float* a    = (const float*)d_in[5];
    const float* lshb = (const float*)d_in[6];

    float* q_out     = (float*)d_out;
    float* means_out = q_out + (size_t)N_PTS * NBUCKET;   // outputs: (q_s, means)

    char* ws = (char*)d_ws;
    short* xhi    = (short*)ws;                               // N*64 = 8 MB
    short* xlo    = xhi + (size_t)N_PTS * OUT_D;              // 8 MB
    short* bfrag  = xlo + (size_t)N_PTS * OUT_D;              // 256 KB
    short* wfrag  = bfrag + (size_t)64 * 64 * 4 * 8;          // 384 KB
    float* xnorm  = (float*)(wfrag + (size_t)16 * 1536 * 8);  // N
    float* mnorm  = xnorm + N_PTS;                            // B
    float* sums   = mnorm + NBUCKET;                          // B*64
    int*   bucket = (int*)(sums + (size_t)NBUCKET * OUT_D);   // N
    int*   order  = bucket + N_PTS;                           // N
    int*   blockhist = order + N_PTS;                         // 64*1024
    int*   blockbase = blockhist + 64 * NBUCKET;              // 64*1024
    int*   base      = blockbase + 64 * NBUCKET;              // 1025
    int*   wsflag    = base + NBUCKET + 1;                    // 2048

    prep_weights<<<96, 256, 0, stream>>>(W1, W2, wfrag);
    mlp_mfma_kernel<<<N_PTS / 128, 256, 0, stream>>>(z, wfrag, b1, b2, a, lshb,
                                                     xhi, xlo, xnorm, bucket, wsflag);
    mlp_fixup_kernel<<<N_PTS / ROWS_A, 256, 0, stream>>>(z, W1, b1, W2, b2, a, lshb, wsflag,
                                                         xhi, xlo, xnorm, bucket);
    hist_kernel<<<64, 256, 0, stream>>>(bucket, blockhist, sums);
    scan_kernel<<<1, 1024, 0, stream>>>(blockhist, base, blockbase);
    scatter_kernel<<<64, 256, 0, stream>>>(bucket, blockbase, order);
    chunksum_kernel<<<256, 256, 0, stream>>>(xhi, xlo, order, bucket, sums);
    means_kernel<<<NBUCKET, 64, 0, stream>>>(sums, base, means_out, mnorm, bfrag);
    q_kernel<<<N_PTS / 32, 256, 0, stream>>>(xhi, xlo, xnorm, bfrag, mnorm, q_out);
}

// Round 17
// 260.108 us; speedup vs baseline: 1.1341x; 1.1313x over previous
//
#include <hip/hip_runtime.h>
#include <hip/hip_bf16.h>

#define N_PTS   65536
#define LATENT  128
#define HIDDEN  512
#define OUT_D   64
#define NBUCKET 1024
#define ROWS_A  32

typedef __attribute__((ext_vector_type(8))) short frag_ab;   // 8 bf16
typedef __attribute__((ext_vector_type(4))) float f32x4;

__device__ __forceinline__ short bf16h(float f) {
    union { float f; unsigned u; } c; c.f = f;
    const unsigned r = (c.u + 0x7FFFu + ((c.u >> 16) & 1u)) >> 16;  // RNE
    return (short)r;
}
__device__ __forceinline__ float bf16tof(short s) {
    union { unsigned u; float f; } c; c.u = ((unsigned)(unsigned short)s) << 16;
    return c.f;
}
__device__ __forceinline__ float fbits(unsigned u) {
    union { unsigned u; float f; } c; c.u = u; return c.f;
}

// ---------------- kernel P: pack W1/W2 -> per-chunk swizzled-linear frag stream ----------------
__global__ __launch_bounds__(256) void prep_weights(
    const float* __restrict__ W1, const float* __restrict__ W2,
    short* __restrict__ wfrag)
{
    const int tid = blockIdx.x * 256 + threadIdx.x;   // 0..24575
    const int c = tid / 1536;
    const int u = tid % 1536;
    frag_ab hi, lo;
    if (u < 1024) {
        const int l = u >> 4, slot = u & 15;
        const int j = slot ^ (l & 7);
        const int ct = j >> 3, ks = (j >> 1) & 3, hl = j & 1;
        const int n = (c * 2 + ct) * 16 + (l & 15);
        const int k0 = ks * 32 + ((l >> 4) << 3);
#pragma unroll
        for (int e = 0; e < 8; ++e) {
            const float wv = W1[(size_t)(k0 + e) * HIDDEN + n];
            const short h = bf16h(wv);
            hi[e] = h;
            lo[e] = bf16h(wv - bf16tof(h));
        }
        ((frag_ab*)wfrag)[(size_t)c * 1536 + u] = hl ? lo : hi;
    } else {
        const int u2 = u - 1024;
        const int l = u2 >> 3, slot = u2 & 7;
        const int j = slot ^ (l & 7);
        const int ot = j >> 1, hl = j & 1;
        const int n = ot * 16 + (l & 15);
#pragma unroll
        for (int e = 0; e < 8; ++e) {
            const int k = c * 32 + ((e >> 2) << 4) + ((l >> 4) << 2) + (e & 3);
            const float wv = W2[(size_t)k * OUT_D + n];
            const short h = bf16h(wv);
            hi[e] = h;
            lo[e] = bf16h(wv - bf16tof(h));
        }
        ((frag_ab*)wfrag)[(size_t)c * 1536 + u] = hl ? lo : hi;
    }
}

// ---------------- kernel A: MFMA MLP (identical to r11; measured D_mlp = 42 us) ----------------
#define XP_STRIDE 512
#define BAND_U   5e-4f

__global__ __launch_bounds__(256, 2) void mlp_mfma_kernel(
    const float* __restrict__ z, const short* __restrict__ wfrag,
    const float* __restrict__ b1, const float* __restrict__ b2,
    const float* __restrict__ a, const float* __restrict__ lsh_b,
    short* __restrict__ xhi, short* __restrict__ xlo,
    float* __restrict__ xnorm_out, int* __restrict__ bucket_out,
    int* __restrict__ wsflag)
{
    __shared__ frag_ab LD[3072];   // 2 x 1536 units = 48 KB
    short* LDs = (short*)LD;
    const int t = threadIdx.x;
    const int l = t & 63, w = t >> 6;
    const int sw = l & 7;
    const int row0 = blockIdx.x * 128 + w * 32;
    const frag_ab* wg = (const frag_ab*)wfrag;

    frag_ab zh[2][4], zl[2][4];
#pragma unroll
    for (int rg = 0; rg < 2; ++rg)
#pragma unroll
        for (int ks = 0; ks < 4; ++ks) {
            const float* src = z + (size_t)(row0 + rg * 16 + (l & 15)) * LATENT
                             + ks * 32 + ((l >> 4) << 3);
            const float4 p0 = *(const float4*)src;
            const float4 p1 = *(const float4*)(src + 4);
            const float v[8] = {p0.x, p0.y, p0.z, p0.w, p1.x, p1.y, p1.z, p1.w};
#pragma unroll
            for (int e = 0; e < 8; ++e) {
                const short h = bf16h(v[e]);
                zh[rg][ks][e] = h;
                zl[rg][ks][e] = bf16h(v[e] - bf16tof(h));
            }
        }

    f32x4 acc2[2][4];
#pragma unroll
    for (int rg = 0; rg < 2; ++rg)
#pragma unroll
        for (int ot = 0; ot < 4; ++ot) acc2[rg][ot] = (f32x4){0.f, 0.f, 0.f, 0.f};

#pragma unroll
    for (int i = 0; i < 6; ++i)
        __builtin_amdgcn_global_load_lds(
            (const __attribute__((address_space(1))) void*)(wg + (w * 6 + i) * 64 + l),
            (__attribute__((address_space(3))) void*)(&LD[(w * 6 + i) * 64]),
            16, 0, 0);
    __syncthreads();

#pragma unroll 1
    for (int c = 0; c < 16; ++c) {
        const int pb = (c & 1) * 1536;
        const int sb = 1536 - pb;
        if (c < 15) {
#pragma unroll
            for (int i = 0; i < 6; ++i)
                __builtin_amdgcn_global_load_lds(
                    (const __attribute__((address_space(1))) void*)(wg + (size_t)(c + 1) * 1536 + (w * 6 + i) * 64 + l),
                    (__attribute__((address_space(3))) void*)(&LD[sb + (w * 6 + i) * 64]),
                    16, 0, 0);
        }

        f32x4 acc1[2][2];
#pragma unroll
        for (int ct_l = 0; ct_l < 2; ++ct_l) {
            frag_ab bh[4], bl[4];
#pragma unroll
            for (int ks = 0; ks < 4; ++ks) {
                bh[ks] = LD[pb + l * 16 + ct_l * 8 + ((ks * 2) ^ sw)];
                bl[ks] = LD[pb + l * 16 + ct_l * 8 + ((ks * 2 + 1) ^ sw)];
            }
#pragma unroll
            for (int rg = 0; rg < 2; ++rg) {
                f32x4 acc = (f32x4){0.f, 0.f, 0.f, 0.f};
#pragma unroll
                for (int ks = 0; ks < 4; ++ks) {
                    acc = __builtin_amdgcn_mfma_f32_16x16x32_bf16(bh[ks], zh[rg][ks], acc, 0, 0, 0);
                    acc = __builtin_amdgcn_mfma_f32_16x16x32_bf16(bl[ks], zh[rg][ks], acc, 0, 0, 0);
                    acc = __builtin_amdgcn_mfma_f32_16x16x32_bf16(bh[ks], zl[rg][ks], acc, 0, 0, 0);
                }
                acc1[ct_l][rg] = acc;
            }
        }

        float4 b1v[2];
#pragma unroll
        for (int ct_l = 0; ct_l < 2; ++ct_l)
            b1v[ct_l] = *(const float4*)&b1[(c * 2 + ct_l) * 16 + ((l >> 4) << 2)];
        frag_ab ah2[2], al2[2];
#pragma unroll
        for (int rg = 0; rg < 2; ++rg)
#pragma unroll
            for (int e = 0; e < 8; ++e) {
                const int tile = e >> 2, r = e & 3;
                const float bb = (r == 0) ? b1v[tile].x : (r == 1) ? b1v[tile].y
                               : (r == 2) ? b1v[tile].z : b1v[tile].w;
                const float hv = fmaxf(acc1[tile][rg][r] + bb, 0.f);
                const short hh = bf16h(hv);
                ah2[rg][e] = hh;
                al2[rg][e] = bf16h(hv - bf16tof(hh));
            }

#pragma unroll
        for (int ot = 0; ot < 4; ++ot) {
            const frag_ab b2h = LD[pb + 1024 + l * 8 + ((ot * 2) ^ sw)];
            const frag_ab b2l = LD[pb + 1024 + l * 8 + ((ot * 2 + 1) ^ sw)];
#pragma unroll
            for (int rg = 0; rg < 2; ++rg) {
                acc2[rg][ot] = __builtin_amdgcn_mfma_f32_16x16x32_bf16(ah2[rg], b2h, acc2[rg][ot], 0, 0, 0);
                acc2[rg][ot] = __builtin_amdgcn_mfma_f32_16x16x32_bf16(al2[rg], b2h, acc2[rg][ot], 0, 0, 0);
                acc2[rg][ot] = __builtin_amdgcn_mfma_f32_16x16x32_bf16(ah2[rg], b2l, acc2[rg][ot], 0, 0, 0);
            }
        }
        __syncthreads();
    }

    float b2v[4], av[4];
#pragma unroll
    for (int ot = 0; ot < 4; ++ot) {
        b2v[ot] = b2[ot * 16 + (l & 15)];
        av[ot]  = a[ot * 16 + (l & 15)];
    }
    const int pbase = w * XP_STRIDE;
    int flagged = 0;
    const float lb = lsh_b[0];
#pragma unroll
    for (int rg = 0; rg < 2; ++rg)
#pragma unroll
        for (int r = 0; r < 4; ++r) {
            float sp = 0.f, np = 0.f;
            const int row_l = rg * 16 + (l >> 4) * 4 + r;
#pragma unroll
            for (int ot = 0; ot < 4; ++ot) {
                const float xv = acc2[rg][ot][r] + b2v[ot];
                sp = fmaf(xv, av[ot], sp);
                np = fmaf(xv, xv, np);
                const int col = ot * 16 + (l & 15);
                const short xh = bf16h(xv);
                LDs[(pbase + row_l * 8 + (col >> 3)) * 8 + (col & 7)] = xh;
                LDs[(pbase + 256 + row_l * 8 + (col >> 3)) * 8 + (col & 7)] = bf16h(xv - bf16tof(xh));
            }
#pragma unroll
            for (int off = 8; off >= 1; off >>= 1) {
                sp += __shfl_xor(sp, off, 16);
                np += __shfl_xor(np, off, 16);
            }
            if ((l & 15) == 0) {
                const int row = row0 + row_l;
                const float v = sp + lb;
                const float u = v * 0.25f;
                const float fl = floorf(u);
                bucket_out[row] = ((int)fl) & (NBUCKET - 1);
                xnorm_out[row] = np;
                const float fr = u - fl;
                if (fr < BAND_U || fr > 1.f - BAND_U) flagged = 1;
            }
        }
    const unsigned long long fb = __ballot(flagged != 0);
    if (l == 0) wsflag[blockIdx.x * 4 + w] = (fb != 0ull) ? 1 : 0;

    frag_ab* xhi8 = (frag_ab*)xhi;
    frag_ab* xlo8 = (frag_ab*)xlo;
#pragma unroll
    for (int j = 0; j < 4; ++j) {
        const int u = l + 64 * j;
        const size_t gidx = (size_t)(row0 + (u >> 3)) * 8 + (u & 7);
        xhi8[gidx] = LD[pbase + u];
        xlo8[gidx] = LD[pbase + 256 + u];
    }
}

// ---------------- kernel A': gated fp32 fixup ----------------
__global__ __launch_bounds__(256, 3) void mlp_fixup_kernel(
    const float* __restrict__ z, const float* __restrict__ W1,
    const float* __restrict__ b1, const float* __restrict__ W2,
    const float* __restrict__ b2, const float* __restrict__ a,
    const float* __restrict__ lsh_b, const int* __restrict__ wsflag,
    short* __restrict__ xhi, short* __restrict__ xlo,
    float* __restrict__ xnorm_out, int* __restrict__ bucket_out)
{
    if (wsflag[blockIdx.x] == 0) return;
    __shared__ float zt[ROWS_A][LATENT];
    __shared__ float ht[ROWS_A][256];
    const int t = threadIdx.x;
    const int row0 = blockIdx.x * ROWS_A;

    {
        const float4* z4 = reinterpret_cast<const float4*>(z + (size_t)row0 * LATENT);
        float4* zt4 = reinterpret_cast<float4*>(&zt[0][0]);
#pragma unroll
        for (int i = 0; i < 4; ++i) zt4[t + 256 * i] = z4[t + 256 * i];
    }
    __syncthreads();

    const int tx = t & 63, ty = t >> 6;
    const int txq = t & 31, tyq = t >> 5;

    float acc2[4][2];
#pragma unroll
    for (int i = 0; i < 4; ++i) { acc2[i][0] = 0.f; acc2[i][1] = 0.f; }

    for (int h = 0; h < 2; ++h) {
        float acc1[8][4];
#pragma unroll
        for (int i = 0; i < 8; ++i)
#pragma unroll
            for (int cc = 0; cc < 4; ++cc) acc1[i][cc] = 0.f;

        const int jbase = h * 256 + tx;
#pragma unroll 2
        for (int k = 0; k < LATENT; k += 4) {
            float wv[4][4];
#pragma unroll
            for (int kk = 0; kk < 4; ++kk)
#pragma unroll
                for (int cc = 0; cc < 4; ++cc)
                    wv[kk][cc] = W1[(size_t)(k + kk) * HIDDEN + jbase + 64 * cc];
            float4 zv[8];
#pragma unroll
            for (int i = 0; i < 8; ++i)
                zv[i] = *reinterpret_cast<const float4*>(&zt[ty * 8 + i][k]);
#pragma unroll
            for (int i = 0; i < 8; ++i)
#pragma unroll
                for (int cc = 0; cc < 4; ++cc) {
                    acc1[i][cc] = fmaf(zv[i].x, wv[0][cc], acc1[i][cc]);
                    acc1[i][cc] = fmaf(zv[i].y, wv[1][cc], acc1[i][cc]);
                    acc1[i][cc] = fmaf(zv[i].z, wv[2][cc], acc1[i][cc]);
                    acc1[i][cc] = fmaf(zv[i].w, wv[3][cc], acc1[i][cc]);
                }
        }
        float bb[4];
#pragma unroll
        for (int cc = 0; cc < 4; ++cc) bb[cc] = b1[jbase + 64 * cc];
#pragma unroll
        for (int i = 0; i < 8; ++i)
#pragma unroll
            for (int cc = 0; cc < 4; ++cc)
                ht[ty * 8 + i][tx + 64 * cc] = fmaxf(acc1[i][cc] + bb[cc], 0.f);
        __syncthreads();

#pragma unroll 2
        for (int k = 0; k < 256; k += 4) {
            float w2v[4][2];
#pragma unroll
            for (int kk = 0; kk < 4; ++kk) {
                w2v[kk][0] = W2[(size_t)(h * 256 + k + kk) * OUT_D + txq];
                w2v[kk][1] = W2[(size_t)(h * 256 + k + kk) * OUT_D + txq + 32];
            }
            float4 hv[4];
#pragma unroll
            for (int i = 0; i < 4; ++i)
                hv[i] = *reinterpret_cast<const float4*>(&ht[tyq * 4 + i][k]);
#pragma unroll
            for (int i = 0; i < 4; ++i)
#pragma unroll
                for (int cc = 0; cc < 2; ++cc) {
                    acc2[i][cc] = fmaf(hv[i].x, w2v[0][cc], acc2[i][cc]);
                    acc2[i][cc] = fmaf(hv[i].y, w2v[1][cc], acc2[i][cc]);
                    acc2[i][cc] = fmaf(hv[i].z, w2v[2][cc], acc2[i][cc]);
                    acc2[i][cc] = fmaf(hv[i].w, w2v[3][cc], acc2[i][cc]);
                }
        }
        __syncthreads();
    }

    const float bb0 = b2[txq], bb1 = b2[txq + 32];
    const float a0 = a[txq], a1 = a[txq + 32];
    const float lb = lsh_b[0];
#pragma unroll
    for (int i = 0; i < 4; ++i) {
        const int row = row0 + tyq * 4 + i;
        const float x0 = acc2[i][0] + bb0;
        const float x1 = acc2[i][1] + bb1;
        const short h0 = bf16h(x0), h1 = bf16h(x1);
        xhi[(size_t)row * OUT_D + txq]      = h0;
        xhi[(size_t)row * OUT_D + txq + 32] = h1;
        xlo[(size_t)row * OUT_D + txq]      = bf16h(x0 - bf16tof(h0));
        xlo[(size_t)row * OUT_D + txq + 32] = bf16h(x1 - bf16tof(h1));

        float sa = fmaf(x0, a0, x1 * a1);
        float sn = fmaf(x0, x0, x1 * x1);
#pragma unroll
        for (int off = 16; off >= 1; off >>= 1) {
            sa += __shfl_xor(sa, off, 32);
            sn += __shfl_xor(sn, off, 32);
        }
        if (txq == 0) {
            const float code = floorf((sa + lb) * 0.25f);
            bucket_out[row] = ((int)code) & (NBUCKET - 1);
            xnorm_out[row] = sn;
        }
    }
}

// ---------------- kernel B1: per-block histograms + zero sums ----------------
__global__ __launch_bounds__(256) void hist_kernel(
    const int* __restrict__ bucket, int* __restrict__ blockhist,
    float* __restrict__ sums)
{
    __shared__ int h[NBUCKET];
    const int t = threadIdx.x, blk = blockIdx.x;
    for (int i = t; i < NBUCKET; i += 256) h[i] = 0;
    for (int i = t; i < NBUCKET; i += 256) sums[blk * NBUCKET + i] = 0.f;
    __syncthreads();
    const int rbase = blk * 1024;
#pragma unroll
    for (int i = 0; i < 4; ++i)
        atomicAdd(&h[bucket[rbase + i * 256 + t]], 1);
    __syncthreads();
    for (int i = t; i < NBUCKET; i += 256)
        blockhist[blk * NBUCKET + i] = h[i];
}

// ---------------- kernel B2: scan (register-preloaded) ----------------
__global__ __launch_bounds__(1024) void scan_kernel(
    const int* __restrict__ blockhist, int* __restrict__ base,
    int* __restrict__ blockbase)
{
    __shared__ int sc[NBUCKET];
    const int b = threadIdx.x;
    int vals[64];
#pragma unroll
    for (int blk = 0; blk < 64; ++blk) vals[blk] = blockhist[blk * NBUCKET + b];
    int c = 0;
#pragma unroll
    for (int blk = 0; blk < 64; ++blk) c += vals[blk];
    sc[b] = c;
    __syncthreads();
    for (int off = 1; off < NBUCKET; off <<= 1) {
        const int add = (b >= off) ? sc[b - off] : 0;
        __syncthreads();
        sc[b] += add;
        __syncthreads();
    }
    const int offset = sc[b] - c;
    base[b] = offset;
    if (b == NBUCKET - 1) base[NBUCKET] = offset + c;
    int run = offset;
#pragma unroll
    for (int blk = 0; blk < 64; ++blk) {
        blockbase[blk * NBUCKET + b] = run;
        run += vals[blk];
    }
}

// ---------------- kernel B3: scatter ----------------
__global__ __launch_bounds__(256) void scatter_kernel(
    const int* __restrict__ bucket, const int* __restrict__ blockbase,
    int* __restrict__ order)
{
    __shared__ int lcur[NBUCKET];
    const int t = threadIdx.x, blk = blockIdx.x;
    for (int i = t; i < NBUCKET; i += 256) lcur[i] = 0;
    __syncthreads();
    const int rbase = blk * 1024;
#pragma unroll
    for (int i = 0; i < 4; ++i) {
        const int row = rbase + i * 256 + t;
        const int bk = bucket[row];
        const int r = atomicAdd(&lcur[bk], 1);
        order[blockbase[blk * NBUCKET + bk] + r] = row;
    }
}

// ---------------- kernel B4: chunked segment sums (r11 version) ----------------
__global__ __launch_bounds__(256) void chunksum_kernel(
    const short* __restrict__ xhi, const short* __restrict__ xlo,
    const int* __restrict__ order, const int* __restrict__ bucket,
    float* __restrict__ sums)
{
    const int t = threadIdx.x, lane = t & 63, w = t >> 6;
    const int c = blockIdx.x * 4 + w;
    const int i0 = c * 64;
    const int ordv = order[i0 + lane];
    const int bktv = bucket[ordv];
    float acc = 0.f;
    int cur = __shfl(bktv, 0, 64);
#pragma unroll 8
    for (int j = 0; j < 64; ++j) {
        const int rb = __shfl(ordv, j, 64);
        const int bb = __shfl(bktv, j, 64);
        if (bb != cur) {
            atomicAdd(&sums[(size_t)cur * OUT_D + lane], acc);
            acc = 0.f; cur = bb;
        }
        acc += bf16tof(xhi[(size_t)rb * OUT_D + lane])
             + bf16tof(xlo[(size_t)rb * OUT_D + lane]);
    }
    atomicAdd(&sums[(size_t)cur * OUT_D + lane], acc);
}

// ---------------- kernel B5: means, mnorm, packed B-fragments ----------------
__global__ __launch_bounds__(64) void means_kernel(
    const float* __restrict__ sums, const int* __restrict__ base,
    float* __restrict__ means_out, float* __restrict__ mnorm,
    short* __restrict__ bfrag)
{
    const int b = blockIdx.x;
    const int k = threadIdx.x;
    const int cnt = base[b + 1] - base[b];
    const float m = sums[b * OUT_D + k] / fmaxf((float)cnt, 1.0f);
    means_out[b * OUT_D + k] = m;

    const short mh = bf16h(m);
    const short ml = bf16h(m - bf16tof(mh));
    const int tile = b >> 4, col = b & 15;
    const int lane = ((k & 31) >> 3) * 16 + col;
    const int f = (k >> 5) * 2;
    const size_t idx = ((size_t)(tile * 64 + lane) * 4 + f) * 8 + (k & 7);
    bfrag[idx] = mh;
    bfrag[idx + 8] = ml;

    float s = m * m;
#pragma unroll
    for (int off = 32; off >= 1; off >>= 1) s += __shfl_xor(s, off, 64);
    if (k == 0) mnorm[b] = s;
}

// ---------------- kernel C: q_s, one-pass + LDS-staged full-line stores ----------------
// Compute identical to r11 (qp bf16 regs). Output staged through a [32][516] LDS tile
// in two 512-col halves; final stores are 1KB-contiguous float4 (full 128B lines).
#define QSTRIDE 516
__global__ __launch_bounds__(256, 2) void q_kernel(
    const short* __restrict__ xhi, const short* __restrict__ xlo,
    const float* __restrict__ xnorm, const short* __restrict__ bfrag,
    const float* __restrict__ mnorm, float* __restrict__ q_out)
{
    __shared__ float qlds[32 * QSTRIDE];   // 64.5 KB
    __shared__ float rs_lds[4][2][16];
    const int t = threadIdx.x;
    const int l = t & 63;
    const int w = t >> 6;
    const int row0 = blockIdx.x * 32;
    const int lrow = (l >> 4) * 4;
    const int lcol = l & 15;

    const frag_ab* xh8 = reinterpret_cast<const frag_ab*>(xhi);
    const frag_ab* xl8 = reinterpret_cast<const frag_ab*>(xlo);
    frag_ab ah[2][2], al[2][2];
#pragma unroll
    for (int s = 0; s < 2; ++s)
#pragma unroll
        for (int kh = 0; kh < 2; ++kh) {
            const size_t idx8 = (size_t)(row0 + s * 16 + lcol) * 8 + kh * 4 + (l >> 4);
            ah[s][kh] = xh8[idx8];
            al[s][kh] = xl8[idx8];
        }

    float xn[2][4];
#pragma unroll
    for (int s = 0; s < 2; ++s)
#pragma unroll
        for (int r = 0; r < 4; ++r) xn[s][r] = xnorm[row0 + s * 16 + lrow + r];

    const frag_ab* bf8 = reinterpret_cast<const frag_ab*>(bfrag);
    unsigned qp[2][16][2];
    float rsp[2][4] = {{0.f,0.f,0.f,0.f},{0.f,0.f,0.f,0.f}};

#pragma unroll
    for (int j = 0; j < 16; ++j) {
        const int bt = w + 4 * j;
        const size_t bb = (size_t)(bt * 64 + l) * 4;
        const frag_ab b0h = bf8[bb + 0];
        const frag_ab b0l = bf8[bb + 1];
        const frag_ab b1h = bf8[bb + 2];
        const frag_ab b1l = bf8[bb + 3];
        const float mn = mnorm[bt * 16 + lcol];

#pragma unroll
        for (int s = 0; s < 2; ++s) {
            f32x4 acc = {0.f, 0.f, 0.f, 0.f};
            acc = __builtin_amdgcn_mfma_f32_16x16x32_bf16(ah[s][0], b0h, acc, 0, 0, 0);
            acc = __builtin_amdgcn_mfma_f32_16x16x32_bf16(ah[s][1], b1h, acc, 0, 0, 0);
            acc = __builtin_amdgcn_mfma_f32_16x16x32_bf16(ah[s][0], b0l, acc, 0, 0, 0);
            acc = __builtin_amdgcn_mfma_f32_16x16x32_bf16(ah[s][1], b1l, acc, 0, 0, 0);
            acc = __builtin_amdgcn_mfma_f32_16x16x32_bf16(al[s][0], b0h, acc, 0, 0, 0);
            acc = __builtin_amdgcn_mfma_f32_16x16x32_bf16(al[s][1], b1h, acc, 0, 0, 0);

            float qq[4];
#pragma unroll
            for (int r = 0; r < 4; ++r) {
                const float d2 = fmaxf(fmaf(-2.f, acc[r], xn[s][r] + mn), 0.f);
                qq[r] = __builtin_amdgcn_rcpf(1.f + d2);
                rsp[s][r] += qq[r];
            }
            qp[s][j][0] = ((unsigned)(unsigned short)bf16h(qq[1]) << 16)
                        | (unsigned)(unsigned short)bf16h(qq[0]);
            qp[s][j][1] = ((unsigned)(unsigned short)bf16h(qq[3]) << 16)
                        | (unsigned)(unsigned short)bf16h(qq[2]);
        }
    }

#pragma unroll
    for (int off = 8; off >= 1; off >>= 1)
#pragma unroll
        for (int s = 0; s < 2; ++s)
#pragma unroll
            for (int r = 0; r < 4; ++r) rsp[s][r] += __shfl_xor(rsp[s][r], off, 16);
    if (lcol == 0) {
#pragma unroll
        for (int s = 0; s < 2; ++s)
#pragma unroll
            for (int r = 0; r < 4; ++r) rs_lds[w][s][lrow + r] = rsp[s][r];
    }
    __syncthreads();

    float inv[2][4];
#pragma unroll
    for (int s = 0; s < 2; ++s)
#pragma unroll
        for (int r = 0; r < 4; ++r) {
            const float tot = rs_lds[0][s][lrow + r] + rs_lds[1][s][lrow + r]
                            + rs_lds[2][s][lrow + r] + rs_lds[3][s][lrow + r];
            inv[s][r] = __builtin_amdgcn_rcpf(tot);
        }

    // staged output: half h covers cols [h*512, h*512+512)
#pragma unroll 1
    for (int half = 0; half < 2; ++half) {
        __syncthreads();   // half 0: after inv; half 1: after previous readout
#pragma unroll
        for (int jj = 0; jj < 8; ++jj) {
            const int j = half * 8 + jj;
            const int bt = w + 4 * j;
            const int colb = bt * 16 + lcol - half * 512;   // 0..511
            const int rbase0 = lrow * QSTRIDE + colb;
#pragma unroll
            for (int s = 0; s < 2; ++s) {
                const unsigned u0 = qp[s][j][0], u1 = qp[s][j][1];
                const int rb = s * 16 * QSTRIDE + rbase0;
                qlds[rb]               = fbits(u0 << 16)         * inv[s][0];
                qlds[rb + QSTRIDE]     = fbits(u0 & 0xFFFF0000u) * inv[s][1];
                qlds[rb + 2 * QSTRIDE] = fbits(u1 << 16)         * inv[s][2];
                qlds[rb + 3 * QSTRIDE] = fbits(u1 & 0xFFFF0000u) * inv[s][3];
            }
        }
        __syncthreads();
        // coalesced readout: 256 threads x 16 float4 = 32 rows x 512 cols
#pragma unroll
        for (int k = 0; k < 16; ++k) {
            const int idx = k * 256 + t;
            const int row = idx >> 7;          // 0..31
            const int c4 = idx & 127;          // 0..127
            const float4 v = *reinterpret_cast<const float4*>(&qlds[row * QSTRIDE + c4 * 4]);
            *reinterpret_cast<float4*>(&q_out[(size_t)(row0 + row) * NBUCKET + half * 512 + c4 * 4]) = v;
        }
    }
}

extern "C" void kernel_launch(void* const* d_in, const int* in_sizes, int n_in,
                              void* d_out, int out_size, void* d_ws, size_t ws_size,
                              hipStream_t stream) {
    const float* z    = (const float*)d_in[0];
    const float* W1   = (const float*)d_in[1];
    const float* b1   = (const float*)d_in[2];
    const float* W2   = (const float*)d_in[3];
    const float* b2   = (const float*)d_in[4];
    const float* a    = (const float*)d_in[5];
    const float* lshb = (const float*)d_in[6];

    float* q_out     = (float*)d_out;
    float* means_out = q_out + (size_t)N_PTS * NBUCKET;   // outputs: (q_s, means)

    char* ws = (char*)d_ws;
    short* xhi    = (short*)ws;                               // N*64 = 8 MB
    short* xlo    = xhi + (size_t)N_PTS * OUT_D;              // 8 MB
    short* bfrag  = xlo + (size_t)N_PTS * OUT_D;              // 256 KB
    short* wfrag  = bfrag + (size_t)64 * 64 * 4 * 8;          // 384 KB
    float* xnorm  = (float*)(wfrag + (size_t)16 * 1536 * 8);  // N
    float* mnorm  = xnorm + N_PTS;                            // B
    float* sums   = mnorm + NBUCKET;                          // B*64
    int*   bucket = (int*)(sums + (size_t)NBUCKET * OUT_D);   // N
    int*   order  = bucket + N_PTS;                           // N
    int*   blockhist = order + N_PTS;                         // 64*1024
    int*   blockbase = blockhist + 64 * NBUCKET;              // 64*1024
    int*   base      = blockbase + 64 * NBUCKET;              // 1025
    int*   wsflag    = base + NBUCKET + 1;                    // 2048

    prep_weights<<<96, 256, 0, stream>>>(W1, W2, wfrag);
    mlp_mfma_kernel<<<N_PTS / 128, 256, 0, stream>>>(z, wfrag, b1, b2, a, lshb,
                                                     xhi, xlo, xnorm, bucket, wsflag);
    mlp_fixup_kernel<<<N_PTS / ROWS_A, 256, 0, stream>>>(z, W1, b1, W2, b2, a, lshb, wsflag,
                                                         xhi, xlo, xnorm, bucket);
    hist_kernel<<<64, 256, 0, stream>>>(bucket, blockhist, sums);
    scan_kernel<<<1, 1024, 0, stream>>>(blockhist, base, blockbase);
    scatter_kernel<<<64, 256, 0, stream>>>(bucket, blockbase, order);
    chunksum_kernel<<<256, 256, 0, stream>>>(xhi, xlo, order, bucket, sums);
    means_kernel<<<NBUCKET, 64, 0, stream>>>(sums, base, means_out, mnorm, bfrag);
    q_kernel<<<N_PTS / 32, 256, 0, stream>>>(xhi, xlo, xnorm, bfrag, mnorm, q_out);
}

// Round 18
// 207.278 us; speedup vs baseline: 1.4231x; 1.2549x over previous
//
#include <hip/hip_runtime.h>
#include <hip/hip_bf16.h>

#define N_PTS   65536
#define LATENT  128
#define HIDDEN  512
#define OUT_D   64
#define NBUCKET 1024
#define ROWS_A  32

typedef __attribute__((ext_vector_type(8))) short frag_ab;   // 8 bf16
typedef __attribute__((ext_vector_type(4))) float f32x4;

__device__ __forceinline__ short bf16h(float f) {
    union { float f; unsigned u; } c; c.f = f;
    const unsigned r = (c.u + 0x7FFFu + ((c.u >> 16) & 1u)) >> 16;  // RNE
    return (short)r;
}
__device__ __forceinline__ float bf16tof(short s) {
    union { unsigned u; float f; } c; c.u = ((unsigned)(unsigned short)s) << 16;
    return c.f;
}

// ---------------- kernel P: pack W1/W2 -> per-chunk swizzled-linear frag stream ----------------
__global__ __launch_bounds__(256) void prep_weights(
    const float* __restrict__ W1, const float* __restrict__ W2,
    short* __restrict__ wfrag)
{
    const int tid = blockIdx.x * 256 + threadIdx.x;   // 0..24575
    const int c = tid / 1536;
    const int u = tid % 1536;
    frag_ab hi, lo;
    if (u < 1024) {
        const int l = u >> 4, slot = u & 15;
        const int j = slot ^ (l & 7);
        const int ct = j >> 3, ks = (j >> 1) & 3, hl = j & 1;
        const int n = (c * 2 + ct) * 16 + (l & 15);
        const int k0 = ks * 32 + ((l >> 4) << 3);
#pragma unroll
        for (int e = 0; e < 8; ++e) {
            const float wv = W1[(size_t)(k0 + e) * HIDDEN + n];
            const short h = bf16h(wv);
            hi[e] = h;
            lo[e] = bf16h(wv - bf16tof(h));
        }
        ((frag_ab*)wfrag)[(size_t)c * 1536 + u] = hl ? lo : hi;
    } else {
        const int u2 = u - 1024;
        const int l = u2 >> 3, slot = u2 & 7;
        const int j = slot ^ (l & 7);
        const int ot = j >> 1, hl = j & 1;
        const int n = ot * 16 + (l & 15);
#pragma unroll
        for (int e = 0; e < 8; ++e) {
            const int k = c * 32 + ((e >> 2) << 4) + ((l >> 4) << 2) + (e & 3);
            const float wv = W2[(size_t)k * OUT_D + n];
            const short h = bf16h(wv);
            hi[e] = h;
            lo[e] = bf16h(wv - bf16tof(h));
        }
        ((frag_ab*)wfrag)[(size_t)c * 1536 + u] = hl ? lo : hi;
    }
}

// ---------------- kernel A: MFMA MLP (r11 structure; x output now fp32) ----------------
#define BAND_U   5e-4f

__global__ __launch_bounds__(256, 2) void mlp_mfma_kernel(
    const float* __restrict__ z, const short* __restrict__ wfrag,
    const float* __restrict__ b1, const float* __restrict__ b2,
    const float* __restrict__ a, const float* __restrict__ lsh_b,
    float* __restrict__ x_out, float* __restrict__ xnorm_out,
    int* __restrict__ bucket_out, int* __restrict__ wsflag)
{
    __shared__ frag_ab LD[3072];   // 2 x 1536 units = 48 KB
    float* LDf = (float*)LD;
    float4* LDf4 = (float4*)LD;
    const int t = threadIdx.x;
    const int l = t & 63, w = t >> 6;
    const int sw = l & 7;
    const int row0 = blockIdx.x * 128 + w * 32;
    const frag_ab* wg = (const frag_ab*)wfrag;

    frag_ab zh[2][4], zl[2][4];
#pragma unroll
    for (int rg = 0; rg < 2; ++rg)
#pragma unroll
        for (int ks = 0; ks < 4; ++ks) {
            const float* src = z + (size_t)(row0 + rg * 16 + (l & 15)) * LATENT
                             + ks * 32 + ((l >> 4) << 3);
            const float4 p0 = *(const float4*)src;
            const float4 p1 = *(const float4*)(src + 4);
            const float v[8] = {p0.x, p0.y, p0.z, p0.w, p1.x, p1.y, p1.z, p1.w};
#pragma unroll
            for (int e = 0; e < 8; ++e) {
                const short h = bf16h(v[e]);
                zh[rg][ks][e] = h;
                zl[rg][ks][e] = bf16h(v[e] - bf16tof(h));
            }
        }

    f32x4 acc2[2][4];
#pragma unroll
    for (int rg = 0; rg < 2; ++rg)
#pragma unroll
        for (int ot = 0; ot < 4; ++ot) acc2[rg][ot] = (f32x4){0.f, 0.f, 0.f, 0.f};

#pragma unroll
    for (int i = 0; i < 6; ++i)
        __builtin_amdgcn_global_load_lds(
            (const __attribute__((address_space(1))) void*)(wg + (w * 6 + i) * 64 + l),
            (__attribute__((address_space(3))) void*)(&LD[(w * 6 + i) * 64]),
            16, 0, 0);
    __syncthreads();

#pragma unroll 1
    for (int c = 0; c < 16; ++c) {
        const int pb = (c & 1) * 1536;
        const int sb = 1536 - pb;
        if (c < 15) {
#pragma unroll
            for (int i = 0; i < 6; ++i)
                __builtin_amdgcn_global_load_lds(
                    (const __attribute__((address_space(1))) void*)(wg + (size_t)(c + 1) * 1536 + (w * 6 + i) * 64 + l),
                    (__attribute__((address_space(3))) void*)(&LD[sb + (w * 6 + i) * 64]),
                    16, 0, 0);
        }

        f32x4 acc1[2][2];
#pragma unroll
        for (int ct_l = 0; ct_l < 2; ++ct_l) {
            frag_ab bh[4], bl[4];
#pragma unroll
            for (int ks = 0; ks < 4; ++ks) {
                bh[ks] = LD[pb + l * 16 + ct_l * 8 + ((ks * 2) ^ sw)];
                bl[ks] = LD[pb + l * 16 + ct_l * 8 + ((ks * 2 + 1) ^ sw)];
            }
#pragma unroll
            for (int rg = 0; rg < 2; ++rg) {
                f32x4 acc = (f32x4){0.f, 0.f, 0.f, 0.f};
#pragma unroll
                for (int ks = 0; ks < 4; ++ks) {
                    acc = __builtin_amdgcn_mfma_f32_16x16x32_bf16(bh[ks], zh[rg][ks], acc, 0, 0, 0);
                    acc = __builtin_amdgcn_mfma_f32_16x16x32_bf16(bl[ks], zh[rg][ks], acc, 0, 0, 0);
                    acc = __builtin_amdgcn_mfma_f32_16x16x32_bf16(bh[ks], zl[rg][ks], acc, 0, 0, 0);
                }
                acc1[ct_l][rg] = acc;
            }
        }

        float4 b1v[2];
#pragma unroll
        for (int ct_l = 0; ct_l < 2; ++ct_l)
            b1v[ct_l] = *(const float4*)&b1[(c * 2 + ct_l) * 16 + ((l >> 4) << 2)];
        frag_ab ah2[2], al2[2];
#pragma unroll
        for (int rg = 0; rg < 2; ++rg)
#pragma unroll
            for (int e = 0; e < 8; ++e) {
                const int tile = e >> 2, r = e & 3;
                const float bb = (r == 0) ? b1v[tile].x : (r == 1) ? b1v[tile].y
                               : (r == 2) ? b1v[tile].z : b1v[tile].w;
                const float hv = fmaxf(acc1[tile][rg][r] + bb, 0.f);
                const short hh = bf16h(hv);
                ah2[rg][e] = hh;
                al2[rg][e] = bf16h(hv - bf16tof(hh));
            }

#pragma unroll
        for (int ot = 0; ot < 4; ++ot) {
            const frag_ab b2h = LD[pb + 1024 + l * 8 + ((ot * 2) ^ sw)];
            const frag_ab b2l = LD[pb + 1024 + l * 8 + ((ot * 2 + 1) ^ sw)];
#pragma unroll
            for (int rg = 0; rg < 2; ++rg) {
                acc2[rg][ot] = __builtin_amdgcn_mfma_f32_16x16x32_bf16(ah2[rg], b2h, acc2[rg][ot], 0, 0, 0);
                acc2[rg][ot] = __builtin_amdgcn_mfma_f32_16x16x32_bf16(al2[rg], b2h, acc2[rg][ot], 0, 0, 0);
                acc2[rg][ot] = __builtin_amdgcn_mfma_f32_16x16x32_bf16(ah2[rg], b2l, acc2[rg][ot], 0, 0, 0);
            }
        }
        __syncthreads();
    }

    // ---- epilogue: x(f32), x.a, ||x||^2, bucket, flag; LDS pack + coalesced f32 store ----
    float b2v[4], av[4];
#pragma unroll
    for (int ot = 0; ot < 4; ++ot) {
        b2v[ot] = b2[ot * 16 + (l & 15)];
        av[ot]  = a[ot * 16 + (l & 15)];
    }
    const int pbase = w * 512;   // per-wave 512 float4 = 8 KB region (weights dead)
    int flagged = 0;
    const float lb = lsh_b[0];
#pragma unroll
    for (int rg = 0; rg < 2; ++rg)
#pragma unroll
        for (int r = 0; r < 4; ++r) {
            float sp = 0.f, np = 0.f;
            const int row_l = rg * 16 + (l >> 4) * 4 + r;
#pragma unroll
            for (int ot = 0; ot < 4; ++ot) {
                const float xv = acc2[rg][ot][r] + b2v[ot];
                sp = fmaf(xv, av[ot], sp);
                np = fmaf(xv, xv, np);
                const int col = ot * 16 + (l & 15);
                LDf[pbase * 4 + row_l * 64 + col] = xv;
            }
#pragma unroll
            for (int off = 8; off >= 1; off >>= 1) {
                sp += __shfl_xor(sp, off, 16);
                np += __shfl_xor(np, off, 16);
            }
            if ((l & 15) == 0) {
                const int row = row0 + row_l;
                const float v = sp + lb;
                const float u = v * 0.25f;
                const float fl = floorf(u);
                bucket_out[row] = ((int)fl) & (NBUCKET - 1);
                xnorm_out[row] = np;
                const float fr = u - fl;
                if (fr < BAND_U || fr > 1.f - BAND_U) flagged = 1;
            }
        }
    const unsigned long long fb = __ballot(flagged != 0);
    if (l == 0) wsflag[blockIdx.x * 4 + w] = (fb != 0ull) ? 1 : 0;

    float4* xo4 = (float4*)x_out;
#pragma unroll
    for (int j = 0; j < 8; ++j) {
        const int u = l + 64 * j;              // 0..511 float4 within wave region
        const int row = u >> 4, c4 = u & 15;
        xo4[(size_t)(row0 + row) * 16 + c4] = LDf4[pbase + row * 16 + c4];
    }
}

// ---------------- kernel A': gated fp32 fixup (x now f32) ----------------
__global__ __launch_bounds__(256, 3) void mlp_fixup_kernel(
    const float* __restrict__ z, const float* __restrict__ W1,
    const float* __restrict__ b1, const float* __restrict__ W2,
    const float* __restrict__ b2, const float* __restrict__ a,
    const float* __restrict__ lsh_b, const int* __restrict__ wsflag,
    float* __restrict__ x_out, float* __restrict__ xnorm_out,
    int* __restrict__ bucket_out)
{
    if (wsflag[blockIdx.x] == 0) return;
    __shared__ float zt[ROWS_A][LATENT];
    __shared__ float ht[ROWS_A][256];
    const int t = threadIdx.x;
    const int row0 = blockIdx.x * ROWS_A;

    {
        const float4* z4 = reinterpret_cast<const float4*>(z + (size_t)row0 * LATENT);
        float4* zt4 = reinterpret_cast<float4*>(&zt[0][0]);
#pragma unroll
        for (int i = 0; i < 4; ++i) zt4[t + 256 * i] = z4[t + 256 * i];
    }
    __syncthreads();

    const int tx = t & 63, ty = t >> 6;
    const int txq = t & 31, tyq = t >> 5;

    float acc2[4][2];
#pragma unroll
    for (int i = 0; i < 4; ++i) { acc2[i][0] = 0.f; acc2[i][1] = 0.f; }

    for (int h = 0; h < 2; ++h) {
        float acc1[8][4];
#pragma unroll
        for (int i = 0; i < 8; ++i)
#pragma unroll
            for (int cc = 0; cc < 4; ++cc) acc1[i][cc] = 0.f;

        const int jbase = h * 256 + tx;
#pragma unroll 2
        for (int k = 0; k < LATENT; k += 4) {
            float wv[4][4];
#pragma unroll
            for (int kk = 0; kk < 4; ++kk)
#pragma unroll
                for (int cc = 0; cc < 4; ++cc)
                    wv[kk][cc] = W1[(size_t)(k + kk) * HIDDEN + jbase + 64 * cc];
            float4 zv[8];
#pragma unroll
            for (int i = 0; i < 8; ++i)
                zv[i] = *reinterpret_cast<const float4*>(&zt[ty * 8 + i][k]);
#pragma unroll
            for (int i = 0; i < 8; ++i)
#pragma unroll
                for (int cc = 0; cc < 4; ++cc) {
                    acc1[i][cc] = fmaf(zv[i].x, wv[0][cc], acc1[i][cc]);
                    acc1[i][cc] = fmaf(zv[i].y, wv[1][cc], acc1[i][cc]);
                    acc1[i][cc] = fmaf(zv[i].z, wv[2][cc], acc1[i][cc]);
                    acc1[i][cc] = fmaf(zv[i].w, wv[3][cc], acc1[i][cc]);
                }
        }
        float bb[4];
#pragma unroll
        for (int cc = 0; cc < 4; ++cc) bb[cc] = b1[jbase + 64 * cc];
#pragma unroll
        for (int i = 0; i < 8; ++i)
#pragma unroll
            for (int cc = 0; cc < 4; ++cc)
                ht[ty * 8 + i][tx + 64 * cc] = fmaxf(acc1[i][cc] + bb[cc], 0.f);
        __syncthreads();

#pragma unroll 2
        for (int k = 0; k < 256; k += 4) {
            float w2v[4][2];
#pragma unroll
            for (int kk = 0; kk < 4; ++kk) {
                w2v[kk][0] = W2[(size_t)(h * 256 + k + kk) * OUT_D + txq];
                w2v[kk][1] = W2[(size_t)(h * 256 + k + kk) * OUT_D + txq + 32];
            }
            float4 hv[4];
#pragma unroll
            for (int i = 0; i < 4; ++i)
                hv[i] = *reinterpret_cast<const float4*>(&ht[tyq * 4 + i][k]);
#pragma unroll
            for (int i = 0; i < 4; ++i)
#pragma unroll
                for (int cc = 0; cc < 2; ++cc) {
                    acc2[i][cc] = fmaf(hv[i].x, w2v[0][cc], acc2[i][cc]);
                    acc2[i][cc] = fmaf(hv[i].y, w2v[1][cc], acc2[i][cc]);
                    acc2[i][cc] = fmaf(hv[i].z, w2v[2][cc], acc2[i][cc]);
                    acc2[i][cc] = fmaf(hv[i].w, w2v[3][cc], acc2[i][cc]);
                }
        }
        __syncthreads();
    }

    const float bb0 = b2[txq], bb1 = b2[txq + 32];
    const float a0 = a[txq], a1 = a[txq + 32];
    const float lb = lsh_b[0];
#pragma unroll
    for (int i = 0; i < 4; ++i) {
        const int row = row0 + tyq * 4 + i;
        const float x0 = acc2[i][0] + bb0;
        const float x1 = acc2[i][1] + bb1;
        x_out[(size_t)row * OUT_D + txq]      = x0;
        x_out[(size_t)row * OUT_D + txq + 32] = x1;

        float sa = fmaf(x0, a0, x1 * a1);
        float sn = fmaf(x0, x0, x1 * x1);
#pragma unroll
        for (int off = 16; off >= 1; off >>= 1) {
            sa += __shfl_xor(sa, off, 32);
            sn += __shfl_xor(sn, off, 32);
        }
        if (txq == 0) {
            const float code = floorf((sa + lb) * 0.25f);
            bucket_out[row] = ((int)code) & (NBUCKET - 1);
            xnorm_out[row] = sn;
        }
    }
}

// ---------------- kernel B1: per-block histograms + zero sums ----------------
__global__ __launch_bounds__(256) void hist_kernel(
    const int* __restrict__ bucket, int* __restrict__ blockhist,
    float* __restrict__ sums)
{
    __shared__ int h[NBUCKET];
    const int t = threadIdx.x, blk = blockIdx.x;
    for (int i = t; i < NBUCKET; i += 256) h[i] = 0;
    for (int i = t; i < NBUCKET; i += 256) sums[blk * NBUCKET + i] = 0.f;
    __syncthreads();
    const int rbase = blk * 1024;
#pragma unroll
    for (int i = 0; i < 4; ++i)
        atomicAdd(&h[bucket[rbase + i * 256 + t]], 1);
    __syncthreads();
    for (int i = t; i < NBUCKET; i += 256)
        blockhist[blk * NBUCKET + i] = h[i];
}

// ---------------- kernel B2: scan + nonzero-bucket compaction ----------------
__global__ __launch_bounds__(1024) void scan_kernel(
    const int* __restrict__ blockhist, int* __restrict__ base,
    int* __restrict__ blockbase, int* __restrict__ nzbucket,
    int* __restrict__ nzcount)
{
    __shared__ int sc[NBUCKET];
    const int b = threadIdx.x;
    int vals[64];
#pragma unroll
    for (int blk = 0; blk < 64; ++blk) vals[blk] = blockhist[blk * NBUCKET + b];
    int c = 0;
#pragma unroll
    for (int blk = 0; blk < 64; ++blk) c += vals[blk];
    sc[b] = c;
    __syncthreads();
    for (int off = 1; off < NBUCKET; off <<= 1) {
        const int add = (b >= off) ? sc[b - off] : 0;
        __syncthreads();
        sc[b] += add;
        __syncthreads();
    }
    const int offset = sc[b] - c;
    base[b] = offset;
    if (b == NBUCKET - 1) base[NBUCKET] = offset + c;
    int run = offset;
#pragma unroll
    for (int blk = 0; blk < 64; ++blk) {
        blockbase[blk * NBUCKET + b] = run;
        run += vals[blk];
    }
    // compaction: list of occupied buckets, ascending (deterministic)
    __syncthreads();
    const int flag = (c > 0) ? 1 : 0;
    sc[b] = flag;
    __syncthreads();
    for (int off = 1; off < NBUCKET; off <<= 1) {
        const int add = (b >= off) ? sc[b - off] : 0;
        __syncthreads();
        sc[b] += add;
        __syncthreads();
    }
    if (flag) nzbucket[sc[b] - 1] = b;
    if (b == NBUCKET - 1) nzcount[0] = sc[NBUCKET - 1];
}

// ---------------- kernel B3: scatter ----------------
__global__ __launch_bounds__(256) void scatter_kernel(
    const int* __restrict__ bucket, const int* __restrict__ blockbase,
    int* __restrict__ order)
{
    __shared__ int lcur[NBUCKET];
    const int t = threadIdx.x, blk = blockIdx.x;
    for (int i = t; i < NBUCKET; i += 256) lcur[i] = 0;
    __syncthreads();
    const int rbase = blk * 1024;
#pragma unroll
    for (int i = 0; i < 4; ++i) {
        const int row = rbase + i * 256 + t;
        const int bk = bucket[row];
        const int r = atomicAdd(&lcur[bk], 1);
        order[blockbase[blk * NBUCKET + bk] + r] = row;
    }
}

// ---------------- kernel B4: chunked segment sums (f32 x) ----------------
__global__ __launch_bounds__(256) void chunksum_kernel(
    const float* __restrict__ x, const int* __restrict__ order,
    const int* __restrict__ bucket, float* __restrict__ sums)
{
    const int t = threadIdx.x, lane = t & 63, w = t >> 6;
    const int c = blockIdx.x * 4 + w;
    const int i0 = c * 64;
    const int ordv = order[i0 + lane];
    const int bktv = bucket[ordv];
    float acc = 0.f;
    int cur = __shfl(bktv, 0, 64);
#pragma unroll 8
    for (int j = 0; j < 64; ++j) {
        const int rb = __shfl(ordv, j, 64);
        const int bb = __shfl(bktv, j, 64);
        if (bb != cur) {
            atomicAdd(&sums[(size_t)cur * OUT_D + lane], acc);
            acc = 0.f; cur = bb;
        }
        acc += x[(size_t)rb * OUT_D + lane];
    }
    atomicAdd(&sums[(size_t)cur * OUT_D + lane], acc);
}

// ---------------- kernel B5: means + mnorm ----------------
__global__ __launch_bounds__(64) void means_kernel(
    const float* __restrict__ sums, const int* __restrict__ base,
    float* __restrict__ means_out, float* __restrict__ mnorm)
{
    const int b = blockIdx.x;
    const int k = threadIdx.x;
    const int cnt = base[b + 1] - base[b];
    const float m = sums[b * OUT_D + k] / fmaxf((float)cnt, 1.0f);
    means_out[b * OUT_D + k] = m;
    float s = m * m;
#pragma unroll
    for (int off = 32; off >= 1; off >>= 1) s += __shfl_xor(s, off, 64);
    if (k == 0) mnorm[b] = s;
}

// ---------------- kernel C: q_s via occupied-bucket sparsity ----------------
// Empty buckets (count==0) have mean=0 -> q = 1/(1+||x||^2), a per-row constant.
// Per block: 32 rows. Pre-phase computes K real q's + row sum (8-thread groups,
// fixed-order reduce -> deterministic). Output: 4-row LDS tiles filled with
// filler*inv, patched with real values, streamed out as full-line float4 stores.
__global__ __launch_bounds__(256, 3) void q_kernel(
    const float* __restrict__ x, const float* __restrict__ xnorm,
    const float* __restrict__ means, const float* __restrict__ mnorm,
    const int* __restrict__ nzbucket, const int* __restrict__ nzcount,
    float* __restrict__ q_out)
{
    __shared__ float xr[32 * 64];       // 8 KB
    __shared__ float qrow[4 * 1024];    // 16 KB
    __shared__ float invv[32], flinv[32];
    const int t = threadIdx.x;
    const int row0 = blockIdx.x * 32;
    const int K = nzcount[0];

    {   // x tile, coalesced
        const float4* x4 = (const float4*)(x + (size_t)row0 * OUT_D);
        float4* xr4 = (float4*)xr;
        xr4[t] = x4[t];
        xr4[t + 256] = x4[t + 256];
    }
    __syncthreads();

    // pre-phase: 8 threads per row; k ascending; all lanes hold full dot after butterfly
    const int r = t >> 3;
    const int sl = t & 7;
    const float xn = xnorm[row0 + r];
    float rsum = 0.f;
    {
        const float4 xa = *(const float4*)&xr[r * 64 + sl * 8];
        const float4 xb = *(const float4*)&xr[r * 64 + sl * 8 + 4];
        for (int k = 0; k < K; ++k) {
            const int bid = nzbucket[k];
            const float4 ma = *(const float4*)&means[(size_t)bid * OUT_D + sl * 8];
            const float4 mb = *(const float4*)&means[(size_t)bid * OUT_D + sl * 8 + 4];
            float d = xa.x * ma.x + xa.y * ma.y + xa.z * ma.z + xa.w * ma.w
                    + xb.x * mb.x + xb.y * mb.y + xb.z * mb.z + xb.w * mb.w;
            d += __shfl_xor(d, 1, 8);
            d += __shfl_xor(d, 2, 8);
            d += __shfl_xor(d, 4, 8);
            const float d2 = fmaxf(xn + mnorm[bid] - 2.f * d, 0.f);
            rsum += __builtin_amdgcn_rcpf(1.f + d2);
        }
    }
    const float filler = __builtin_amdgcn_rcpf(1.f + xn);
    const float tot = fmaf((float)(NBUCKET - K), filler, rsum);
    if (sl == 0) {
        const float iv = __builtin_amdgcn_rcpf(tot);
        invv[r] = iv;
        flinv[r] = filler * iv;
    }
    __syncthreads();

    // output: 8 groups of 4 rows
#pragma unroll 1
    for (int g = 0; g < 8; ++g) {
        const int rr0 = g * 4;
        // fill with per-row filler*inv
#pragma unroll
        for (int i = 0; i < 4; ++i) {
            const int idx = i * 256 + t;          // 0..1023 float4
            const float fv = flinv[rr0 + (idx >> 8)];
            ((float4*)qrow)[idx] = (float4){fv, fv, fv, fv};
        }
        __syncthreads();
        // patch real buckets (recompute dot per patch; K*4 patches)
        for (int p = t; p < K * 4; p += 256) {
            const int k = p >> 2, rr = p & 3;
            const int bid = nzbucket[k];
            const float* xp = &xr[(rr0 + rr) * 64];
            const float* mp = &means[(size_t)bid * OUT_D];
            float d = 0.f;
#pragma unroll 16
            for (int e = 0; e < 64; ++e) d = fmaf(xp[e], mp[e], d);
            const float d2 = fmaxf(xnorm[row0 + rr0 + rr] + mnorm[bid] - 2.f * d, 0.f);
            qrow[rr * 1024 + bid] = __builtin_amdgcn_rcpf(1.f + d2) * invv[rr0 + rr];
        }
        __syncthreads();
        // stream out: each iteration writes one full row (4 KB contiguous)
#pragma unroll
        for (int i = 0; i < 4; ++i) {
            const int idx = i * 256 + t;
            const int rr = idx >> 8, c4 = idx & 255;
            ((float4*)(q_out + (size_t)(row0 + rr0 + rr) * NBUCKET))[c4] =
                ((const float4*)(qrow + rr * 1024))[c4];
        }
        __syncthreads();
    }
}

extern "C" void kernel_launch(void* const* d_in, const int* in_sizes, int n_in,
                              void* d_out, int out_size, void* d_ws, size_t ws_size,
                              hipStream_t stream) {
    const float* z    = (const float*)d_in[0];
    const float* W1   = (const float*)d_in[1];
    const float* b1   = (const float*)d_in[2];
    const float* W2   = (const float*)d_in[3];
    const float* b2   = (const float*)d_in[4];
    const float* a    = (const float*)d_in[5];
    const float* lshb = (const float*)d_in[6];

    float* q_out     = (float*)d_out;
    float* means_out = q_out + (size_t)N_PTS * NBUCKET;   // outputs: (q_s, means)

    char* ws = (char*)d_ws;
    float* x      = (float*)ws;                               // N*64 f32 = 16 MB
    short* wfrag  = (short*)(x + (size_t)N_PTS * OUT_D);      // 384 KB
    float* xnorm  = (float*)(wfrag + (size_t)16 * 1536 * 8);  // N
    float* mnorm  = xnorm + N_PTS;                            // B
    float* sums   = mnorm + NBUCKET;                          // B*64
    int*   bucket = (int*)(sums + (size_t)NBUCKET * OUT_D);   // N
    int*   order  = bucket + N_PTS;                           // N
    int*   blockhist = order + N_PTS;                         // 64*1024
    int*   blockbase = blockhist + 64 * NBUCKET;              // 64*1024
    int*   base      = blockbase + 64 * NBUCKET;              // 1025
    int*   wsflag    = base + NBUCKET + 1;                    // 2048
    int*   nzbucket  = wsflag + 2048;                         // 1024
    int*   nzcount   = nzbucket + NBUCKET;                    // 1

    prep_weights<<<96, 256, 0, stream>>>(W1, W2, wfrag);
    mlp_mfma_kernel<<<N_PTS / 128, 256, 0, stream>>>(z, wfrag, b1, b2, a, lshb,
                                                     x, xnorm, bucket, wsflag);
    mlp_fixup_kernel<<<N_PTS / ROWS_A, 256, 0, stream>>>(z, W1, b1, W2, b2, a, lshb, wsflag,
                                                         x, xnorm, bucket);
    hist_kernel<<<64, 256, 0, stream>>>(bucket, blockhist, sums);
    scan_kernel<<<1, 1024, 0, stream>>>(blockhist, base, blockbase, nzbucket, nzcount);
    scatter_kernel<<<64, 256, 0, stream>>>(bucket, blockbase, order);
    chunksum_kernel<<<256, 256, 0, stream>>>(x, order, bucket, sums);
    means_kernel<<<NBUCKET, 64, 0, stream>>>(sums, base, means_out, mnorm);
    q_kernel<<<N_PTS / 32, 256, 0, stream>>>(x, xnorm, means_out, mnorm,
                                             nzbucket, nzcount, q_out);
}